// Round 15
// baseline (183.110 us; speedup 1.0000x reference)
//
#include <hip/hip_runtime.h>

#define S_ 2304   // 48*48

typedef unsigned short u16;
typedef __attribute__((ext_vector_type(8))) short bf16x8;
typedef __attribute__((ext_vector_type(4))) float f32x4;

static __device__ __forceinline__ u16 f2bf(float x) {
  union { float f; unsigned u; } v; v.f = x;
  unsigned r = v.u + 0x7FFFu + ((v.u >> 16) & 1u);
  return (u16)(r >> 16);
}
static __device__ __forceinline__ float bf2f(u16 h) {
  union { unsigned u; float f; } v; v.u = ((unsigned)h) << 16; return v.f;
}

// ---------------------------------------------------------------------------
// Prep: weight split (blocks 0..255) + x split-transpose h-only (256..831).
// ---------------------------------------------------------------------------
__global__ __launch_bounds__(256) void prep_kernel(
    const float* __restrict__ w0, u16* __restrict__ wh0, u16* __restrict__ wl0,
    const float* __restrict__ w1, u16* __restrict__ wh1, u16* __restrict__ wl1,
    const float* __restrict__ x, u16* __restrict__ xTh)
{
  __shared__ u16 tile[64][65];
  const int bid = blockIdx.x;
  const int tid = threadIdx.x;
  if (bid < 256) {
    const float* w; u16 *wh, *wl; int id;
    if (bid < 192) { w = w0; wh = wh0; wl = wl0; id = bid * 256 + tid; }
    else { w = w1; wh = wh1; wl = wl1; id = (bid - 192) * 256 + tid; }
    float4 v = ((const float4*)w)[id];
    short4 h, l;
    float f[4] = {v.x, v.y, v.z, v.w};
    u16 hh[4], ll[4];
#pragma unroll
    for (int q = 0; q < 4; q++) {
      hh[q] = f2bf(f[q]);
      ll[q] = f2bf(f[q] - bf2f(hh[q]));
    }
    h.x = hh[0]; h.y = hh[1]; h.z = hh[2]; h.w = hh[3];
    l.x = ll[0]; l.y = ll[1]; l.z = ll[2]; l.w = ll[3];
    ((short4*)wh)[id] = h;
    ((short4*)wl)[id] = l;
    return;
  }
  const int bid2 = bid - 256;
  const int s0 = (bid2 % 36) * 64, c0 = ((bid2 / 36) % 4) * 64, b = bid2 / 144;
  const float* inb = x + (size_t)b * 256 * S_;
  u16* oh = xTh + (size_t)b * S_ * 256;
#pragma unroll
  for (int it = 0; it < 4; it++) {
    int id = tid + it * 256;
    int c = id >> 4, s4 = (id & 15) * 4;
    float4 v = *(const float4*)&inb[(size_t)(c0 + c) * S_ + s0 + s4];
    tile[s4 + 0][c] = f2bf(v.x);
    tile[s4 + 1][c] = f2bf(v.y);
    tile[s4 + 2][c] = f2bf(v.z);
    tile[s4 + 3][c] = f2bf(v.w);
  }
  __syncthreads();
#pragma unroll
  for (int it = 0; it < 4; it++) {
    int id = tid + it * 256;
    int s = id >> 4, c4 = (id & 15) * 4;
    short4 h;
    h.x = (short)tile[s][c4 + 0]; h.y = (short)tile[s][c4 + 1];
    h.z = (short)tile[s][c4 + 2]; h.w = (short)tile[s][c4 + 3];
    *(short4*)&oh[(size_t)(s0 + s) * 256 + c0 + c4] = h;
  }
}

// ---------------------------------------------------------------------------
// Split-transpose (h+l) for y before proj. Grid (36,4,4).
// ---------------------------------------------------------------------------
__global__ __launch_bounds__(256) void split_transpose_kernel(
    const float* __restrict__ in, u16* __restrict__ outh, u16* __restrict__ outl)
{
  __shared__ unsigned tile[64][65];
  const int s0 = blockIdx.x * 64, c0 = blockIdx.y * 64, b = blockIdx.z;
  const float* inb = in + (size_t)b * 256 * S_;
  u16* oh = outh + (size_t)b * S_ * 256;
  u16* ol = outl + (size_t)b * S_ * 256;
  const int tid = threadIdx.x;
#pragma unroll
  for (int it = 0; it < 4; it++) {
    int id = tid + it * 256;
    int c = id >> 4, s4 = (id & 15) * 4;
    float4 v = *(const float4*)&inb[(size_t)(c0 + c) * S_ + s0 + s4];
    float f[4] = {v.x, v.y, v.z, v.w};
#pragma unroll
    for (int q = 0; q < 4; q++) {
      u16 h = f2bf(f[q]);
      u16 l = f2bf(f[q] - bf2f(h));
      tile[s4 + q][c] = (unsigned)h | ((unsigned)l << 16);
    }
  }
  __syncthreads();
#pragma unroll
  for (int it = 0; it < 4; it++) {
    int id = tid + it * 256;
    int s = id >> 4, c4 = (id & 15) * 4;
    short4 h, l;
    unsigned p0 = tile[s][c4 + 0], p1 = tile[s][c4 + 1];
    unsigned p2 = tile[s][c4 + 2], p3 = tile[s][c4 + 3];
    h.x = (short)(p0 & 0xffff); h.y = (short)(p1 & 0xffff);
    h.z = (short)(p2 & 0xffff); h.w = (short)(p3 & 0xffff);
    l.x = (short)(p0 >> 16); l.y = (short)(p1 >> 16);
    l.z = (short)(p2 >> 16); l.w = (short)(p3 >> 16);
    *(short4*)&oh[(size_t)(s0 + s) * 256 + c0 + c4] = h;
    *(short4*)&ol[(size_t)(s0 + s) * 256 + c0 + c4] = l;
  }
}

// ---------------------------------------------------------------------------
// MFMA split-bf16 GEMM (r10 form), XLO=false: Out=(Wh+Wl)*Xh. BM=64 BN=128.
// ---------------------------------------------------------------------------
template <bool XLO>
__global__ __launch_bounds__(256) void gemm_mfma_kernel(
    const u16* __restrict__ Wh, const u16* __restrict__ Wl,
    const float* __restrict__ bias,
    const u16* __restrict__ XTh, const u16* __restrict__ XTl,
    float* __restrict__ Out, int M)
{
  __shared__ u16 wAh[2][64 * 40];
  __shared__ u16 wAl[2][64 * 40];
  const int MB = M >> 6;
  const int xcd = blockIdx.x & 7;
  const int idx = blockIdx.x >> 3;
  const int g = xcd * 9 + idx / MB;
  const int mb = idx % MB;
  const int nb = g % 18, b = g / 18;
  const int m0 = mb * 64, n0 = nb * 128;
  const int tid = threadIdx.x;
  const int wv = tid >> 6, lane = tid & 63;
  const int lr = lane & 15, lg = lane >> 4;
  const bf16x8 zv = {0, 0, 0, 0, 0, 0, 0, 0};

  const u16* xbh = XTh + ((size_t)b * S_ + n0 + wv * 32) * 256;
  const u16* xbl = XTl + ((size_t)b * S_ + n0 + wv * 32) * 256;

  f32x4 acc[4][2];
#pragma unroll
  for (int mt = 0; mt < 4; mt++)
#pragma unroll
    for (int nt = 0; nt < 2; nt++) acc[mt][nt] = (f32x4){0.f, 0.f, 0.f, 0.f};

#define STAGE_W(t, buf)                                                      \
  {                                                                          \
    _Pragma("unroll")                                                        \
    for (int r = 0; r < 2; r++) {                                            \
      int id = tid + r * 256;                                                \
      int m = id >> 3, k4 = (id & 7) * 4;                                    \
      *(short4*)&wAh[buf][m * 40 + k4] =                                     \
          *(const short4*)&Wh[(size_t)(m0 + m) * 256 + (t) * 32 + k4];       \
      *(short4*)&wAl[buf][m * 40 + k4] =                                     \
          *(const short4*)&Wl[(size_t)(m0 + m) * 256 + (t) * 32 + k4];       \
    }                                                                        \
  }

  STAGE_W(0, 0);
  bf16x8 cbh[2], cbl[2];
#pragma unroll
  for (int nt = 0; nt < 2; nt++) {
    size_t off = (size_t)(nt * 16 + lr) * 256 + lg * 8;
    cbh[nt] = *(const bf16x8*)&xbh[off];
    if (XLO) cbl[nt] = *(const bf16x8*)&xbl[off];
  }
  __syncthreads();

  for (int t = 0; t < 8; t++) {
    int buf = t & 1;
    if (t < 7) STAGE_W(t + 1, buf ^ 1);

    bf16x8 nbh[2], nbl[2];
    if (t < 7) {
#pragma unroll
      for (int nt = 0; nt < 2; nt++) {
        size_t off = (size_t)(nt * 16 + lr) * 256 + (t + 1) * 32 + lg * 8;
        nbh[nt] = *(const bf16x8*)&xbh[off];
        if (XLO) nbl[nt] = *(const bf16x8*)&xbl[off];
      }
    } else {
#pragma unroll
      for (int nt = 0; nt < 2; nt++) { nbh[nt] = zv; if (XLO) nbl[nt] = zv; }
    }

    bf16x8 ah[4], al[4];
#pragma unroll
    for (int mt = 0; mt < 4; mt++) {
      ah[mt] = *(const bf16x8*)&wAh[buf][(mt * 16 + lr) * 40 + lg * 8];
      al[mt] = *(const bf16x8*)&wAl[buf][(mt * 16 + lr) * 40 + lg * 8];
    }
#pragma unroll
    for (int mt = 0; mt < 4; mt++)
#pragma unroll
      for (int nt = 0; nt < 2; nt++) {
        acc[mt][nt] = __builtin_amdgcn_mfma_f32_16x16x32_bf16(ah[mt], cbh[nt], acc[mt][nt], 0, 0, 0);
        if (XLO)
          acc[mt][nt] = __builtin_amdgcn_mfma_f32_16x16x32_bf16(ah[mt], cbl[nt], acc[mt][nt], 0, 0, 0);
        acc[mt][nt] = __builtin_amdgcn_mfma_f32_16x16x32_bf16(al[mt], cbh[nt], acc[mt][nt], 0, 0, 0);
      }
    __syncthreads();
#pragma unroll
    for (int nt = 0; nt < 2; nt++) { cbh[nt] = nbh[nt]; if (XLO) cbl[nt] = nbl[nt]; }
  }

  float* ob = Out + (size_t)b * M * S_;
#pragma unroll
  for (int mt = 0; mt < 4; mt++) {
    float4 b4 = *(const float4*)&bias[m0 + mt * 16 + lg * 4];
    float bv[4] = {b4.x, b4.y, b4.z, b4.w};
#pragma unroll
    for (int nt = 0; nt < 2; nt++) {
      int s = n0 + wv * 32 + nt * 16 + lr;
#pragma unroll
      for (int r = 0; r < 4; r++) {
        int m = m0 + mt * 16 + lg * 4 + r;
        ob[(size_t)m * S_ + s] = acc[mt][nt][r] + bv[r];
      }
    }
  }
#undef STAGE_W
}

// ---------------------------------------------------------------------------
// Proj GEMM, BN=64 (576 blocks for occupancy). 3-term.
// ---------------------------------------------------------------------------
__global__ __launch_bounds__(256) void gemm_n64_kernel(
    const u16* __restrict__ Wh, const u16* __restrict__ Wl,
    const float* __restrict__ bias,
    const u16* __restrict__ XTh, const u16* __restrict__ XTl,
    float* __restrict__ Out)
{
  __shared__ u16 wAh[2][64 * 40];
  __shared__ u16 wAl[2][64 * 40];
  const int M = 256, MB = 4;
  const int xcd = blockIdx.x & 7;
  const int idx = blockIdx.x >> 3;
  const int g = xcd * 18 + idx / MB;
  const int mb = idx % MB;
  const int nb = g % 36, b = g / 36;
  const int m0 = mb * 64, n0 = nb * 64;
  const int tid = threadIdx.x;
  const int wv = tid >> 6, lane = tid & 63;
  const int wm = wv >> 1, wsd = wv & 1;
  const int lr = lane & 15, lg = lane >> 4;
  const bf16x8 zv = {0, 0, 0, 0, 0, 0, 0, 0};

  const u16* xbh = XTh + ((size_t)b * S_ + n0 + wsd * 32) * 256;
  const u16* xbl = XTl + ((size_t)b * S_ + n0 + wsd * 32) * 256;

  f32x4 acc[2][2];
#pragma unroll
  for (int mt = 0; mt < 2; mt++)
#pragma unroll
    for (int nt = 0; nt < 2; nt++) acc[mt][nt] = (f32x4){0.f, 0.f, 0.f, 0.f};

#define STAGE_W(t, buf)                                                      \
  {                                                                          \
    _Pragma("unroll")                                                        \
    for (int r = 0; r < 2; r++) {                                            \
      int id = tid + r * 256;                                                \
      int m = id >> 3, k4 = (id & 7) * 4;                                    \
      *(short4*)&wAh[buf][m * 40 + k4] =                                     \
          *(const short4*)&Wh[(size_t)(m0 + m) * 256 + (t) * 32 + k4];       \
      *(short4*)&wAl[buf][m * 40 + k4] =                                     \
          *(const short4*)&Wl[(size_t)(m0 + m) * 256 + (t) * 32 + k4];       \
    }                                                                        \
  }

  STAGE_W(0, 0);
  bf16x8 cbh[2], cbl[2];
#pragma unroll
  for (int nt = 0; nt < 2; nt++) {
    size_t off = (size_t)(nt * 16 + lr) * 256 + lg * 8;
    cbh[nt] = *(const bf16x8*)&xbh[off];
    cbl[nt] = *(const bf16x8*)&xbl[off];
  }
  __syncthreads();

  for (int t = 0; t < 8; t++) {
    int buf = t & 1;
    if (t < 7) STAGE_W(t + 1, buf ^ 1);

    bf16x8 nbh[2], nbl[2];
    if (t < 7) {
#pragma unroll
      for (int nt = 0; nt < 2; nt++) {
        size_t off = (size_t)(nt * 16 + lr) * 256 + (t + 1) * 32 + lg * 8;
        nbh[nt] = *(const bf16x8*)&xbh[off];
        nbl[nt] = *(const bf16x8*)&xbl[off];
      }
    } else {
#pragma unroll
      for (int nt = 0; nt < 2; nt++) { nbh[nt] = zv; nbl[nt] = zv; }
    }

    bf16x8 ah[2], al[2];
#pragma unroll
    for (int mt = 0; mt < 2; mt++) {
      ah[mt] = *(const bf16x8*)&wAh[buf][(wm * 32 + mt * 16 + lr) * 40 + lg * 8];
      al[mt] = *(const bf16x8*)&wAl[buf][(wm * 32 + mt * 16 + lr) * 40 + lg * 8];
    }
#pragma unroll
    for (int mt = 0; mt < 2; mt++)
#pragma unroll
      for (int nt = 0; nt < 2; nt++) {
        acc[mt][nt] = __builtin_amdgcn_mfma_f32_16x16x32_bf16(ah[mt], cbh[nt], acc[mt][nt], 0, 0, 0);
        acc[mt][nt] = __builtin_amdgcn_mfma_f32_16x16x32_bf16(ah[mt], cbl[nt], acc[mt][nt], 0, 0, 0);
        acc[mt][nt] = __builtin_amdgcn_mfma_f32_16x16x32_bf16(al[mt], cbh[nt], acc[mt][nt], 0, 0, 0);
      }
    __syncthreads();
#pragma unroll
    for (int nt = 0; nt < 2; nt++) { cbh[nt] = nbh[nt]; cbl[nt] = nbl[nt]; }
  }

  float* ob = Out + (size_t)b * M * S_;
#pragma unroll
  for (int mt = 0; mt < 2; mt++) {
    float4 b4 = *(const float4*)&bias[m0 + wm * 32 + mt * 16 + lg * 4];
    float bv[4] = {b4.x, b4.y, b4.z, b4.w};
#pragma unroll
    for (int nt = 0; nt < 2; nt++) {
      int s = n0 + wsd * 32 + nt * 16 + lr;
#pragma unroll
      for (int r = 0; r < 4; r++) {
        int m = m0 + wm * 32 + mt * 16 + lg * 4 + r;
        ob[(size_t)m * S_ + s] = acc[mt][nt][r] + bv[r];
      }
    }
  }
#undef STAGE_W
}

// ---------------------------------------------------------------------------
// Scores, wave-independent: one wave = one (b,n,h) task, ZERO barriers.
// lane = w owns the full reduction axis in registers -> softmax is entirely
// lane-local (no LDS, no shuffles). 3072 wave-tasks (1536 row + 1536 col),
// 768 blocks x 4 waves, XCD-swizzled so the 24 blocks sharing one (b,n)'s
// rcv slice land on one XCD's L2.
// ---------------------------------------------------------------------------
__global__ __launch_bounds__(256) void scores_kernel(
    const float* __restrict__ rcv, u16* __restrict__ arF, u16* __restrict__ awF)
{
  const int tid = threadIdx.x;
  const int wave = tid >> 6, lane = tid & 63;
  const int xcd = blockIdx.x & 7, idx = blockIdx.x >> 3;
  const int g = xcd * 96 + idx;          // 0..767
  const int t = g * 4 + wave;            // 0..3071
  const int isRow = t < 1536;
  const int tt = isRow ? t : t - 1536;
  const int b = tt / 384, n = (tt / 48) & 7, h = tt % 48;
  if (lane >= 48) return;
  const int w = lane;
  const int nt = w >> 4, lo = w & 15;

  if (isRow) {
    // S[i] = SCALE * sum_d rq[d,i,w] * rk[d,h,w]; softmax over i (lane-local)
    const float* base = rcv + ((size_t)b * 768 + n * 96) * S_;   // rq; rk at +16*S_
    float rk[16];
#pragma unroll
    for (int d = 0; d < 16; d++)
      rk[d] = base[(size_t)(16 + d) * S_ + h * 48 + w];
    float s[48];
#pragma unroll 4
    for (int i = 0; i < 48; i++) {
      float acc = 0.f;
#pragma unroll
      for (int d = 0; d < 16; d++)
        acc += base[(size_t)d * S_ + i * 48 + w] * rk[d];
      s[i] = acc * 0.25f;
    }
    float m = -1e30f;
#pragma unroll
    for (int i = 0; i < 48; i++) m = fmaxf(m, s[i]);
    float sum = 0.f;
#pragma unroll
    for (int i = 0; i < 48; i++) { s[i] = __expf(s[i] - m); sum += s[i]; }
    float rs = 1.0f / sum;
    // arF[h]: (nt*3+mt)*256 + (lo+16*lg)*4 + e  holds s[mt*16+lg*4+e]
    u16* dst = arF + ((size_t)(b * 8 + n) * 48 + h) * 2304;
#pragma unroll
    for (int mt = 0; mt < 3; mt++)
#pragma unroll
      for (int lg = 0; lg < 4; lg++) {
        int i0 = mt * 16 + lg * 4;
        short4 o;
        o.x = (short)f2bf(s[i0 + 0] * rs);
        o.y = (short)f2bf(s[i0 + 1] * rs);
        o.z = (short)f2bf(s[i0 + 2] * rs);
        o.w = (short)f2bf(s[i0 + 3] * rs);
        *(short4*)&dst[(nt * 3 + mt) * 256 + (lo + 16 * lg) * 4] = o;
      }
  } else {
    // T[j] = SCALE * sum_d ck[d,h,w] * cq[d,h,j]; softmax over j (lane-local)
    const float* base = rcv + ((size_t)b * 768 + n * 96 + 32) * S_;  // cq; ck +16*S_
    float ckr[16];
#pragma unroll
    for (int d = 0; d < 16; d++)
      ckr[d] = base[(size_t)(16 + d) * S_ + h * 48 + w];
    float tj[48];
#pragma unroll 4
    for (int j = 0; j < 48; j++) {
      float acc = 0.f;
#pragma unroll
      for (int d = 0; d < 16; d++)
        acc += ckr[d] * base[(size_t)d * S_ + h * 48 + j];   // uniform (scalar) loads
      tj[j] = acc * 0.25f;
    }
    float m = -1e30f;
#pragma unroll
    for (int j = 0; j < 48; j++) m = fmaxf(m, tj[j]);
    float sum = 0.f;
#pragma unroll
    for (int j = 0; j < 48; j++) { tj[j] = __expf(tj[j] - m); sum += tj[j]; }
    float rs = 1.0f / sum;
    // awF[h]: (nt*2+ks)*512 + (lo+16*lg)*8 + e holds t[ks*32+lg*8+e] (0 if j>=48)
    u16* dst = awF + ((size_t)(b * 8 + n) * 48 + h) * 3072;
#pragma unroll
    for (int ks = 0; ks < 2; ks++)
#pragma unroll
      for (int lg = 0; lg < 4; lg++) {
        int j0 = ks * 32 + lg * 8;
        u16 t8[8];
#pragma unroll
        for (int e = 0; e < 8; e++) {
          int j = j0 + e;
          t8[e] = (j < 48) ? f2bf(tj[j] * rs) : (u16)0;
        }
        short4 o0, o1;
        o0.x = (short)t8[0]; o0.y = (short)t8[1]; o0.z = (short)t8[2]; o0.w = (short)t8[3];
        o1.x = (short)t8[4]; o1.y = (short)t8[5]; o1.z = (short)t8[6]; o1.w = (short)t8[7];
        int off = (nt * 2 + ks) * 512 + (lo + 16 * lg) * 8;
        *(short4*)&dst[off] = o0;
        *(short4*)&dst[off + 4] = o1;
      }
  }
}

// ---------------------------------------------------------------------------
// Main contraction + PE conv (verbatim r14 body).
// ---------------------------------------------------------------------------
__global__ __launch_bounds__(256) void attn_main_kernel(
    const float* __restrict__ rcv, const u16* __restrict__ arF,
    const u16* __restrict__ awF, const float* __restrict__ pe_w,
    const float* __restrict__ pe_b, float* __restrict__ y)
{
  __shared__ u16 vA[96 * 72];         // 13824 B
  const int id0 = blockIdx.x;
  const int n = id0 & 7;              // XCD swizzle
  const int rest = id0 >> 3;          // 0..255
  const int b = rest >> 6;
  const int inner = rest & 63;
  const int dchunk = inner >> 2;      // 0..15 (2 planes each)
  const int hc = inner & 3;
  const int tid = threadIdx.x;
  const int wave = tid >> 6, lane = tid & 63;
  const int dl = wave >> 1, half = wave & 1;
  const int h0 = hc * 12 + half * 6;
  const int lr = lane & 15, lg = lane >> 4;

  for (int id = tid; id < 96 * 24; id += 256) {
    int row = id / 24, col = 48 + id % 24;
    vA[row * 72 + col] = 0;
  }
  const float* vbase = rcv + ((size_t)b * 768 + n * 96 + 64 + dchunk * 2) * S_;
  for (int id = tid; id < 1152; id += 256) {
    int dl2 = id / 576, rem = id % 576;
    int i = rem / 12, j4 = (rem % 12) * 4;
    float4 v = *(const float4*)&vbase[(size_t)dl2 * S_ + i * 48 + j4];
    short4 s;
    s.x = (short)f2bf(v.x); s.y = (short)f2bf(v.y);
    s.z = (short)f2bf(v.z); s.w = (short)f2bf(v.w);
    *(short4*)&vA[(dl2 * 48 + i) * 72 + j4] = s;
  }
  __syncthreads();   // the only barrier

  const size_t bn48 = (size_t)(b * 8 + n) * 48;
  const int c = n * 32 + dchunk * 2 + dl;
  float pw[9];
#pragma unroll
  for (int t = 0; t < 9; t++) pw[t] = pe_w[c * 9 + t];
  const float pb = pe_b[c];
  float* yg = y + ((size_t)b * 256 + c) * S_;
  const int vrow0 = dl * 48;

  for (int hh = 0; hh < 6; hh++) {
    int h = h0 + hh;
    const u16* awg = awF + (bn48 + h) * 3072;
    const u16* arg = arF + (bn48 + h) * 2304;

    bf16x8 bf0[3], bf1[3];
#pragma unroll
    for (int nt = 0; nt < 3; nt++) {
      bf0[nt] = *(const bf16x8*)&awg[nt * 1024 + lane * 8];
      bf1[nt] = *(const bf16x8*)&awg[nt * 1024 + 512 + lane * 8];
    }

    f32x4 acc[3][3];
#pragma unroll
    for (int mt = 0; mt < 3; mt++)
#pragma unroll
      for (int nt = 0; nt < 3; nt++) acc[mt][nt] = (f32x4){0.f, 0.f, 0.f, 0.f};

#pragma unroll
    for (int mt = 0; mt < 3; mt++) {
      bf16x8 a0 = *(const bf16x8*)&vA[(vrow0 + mt * 16 + lr) * 72 + lg * 8];
      bf16x8 a1 = *(const bf16x8*)&vA[(vrow0 + mt * 16 + lr) * 72 + 32 + lg * 8];
#pragma unroll
      for (int nt = 0; nt < 3; nt++) {
        acc[mt][nt] = __builtin_amdgcn_mfma_f32_16x16x32_bf16(a0, bf0[nt], acc[mt][nt], 0, 0, 0);
        acc[mt][nt] = __builtin_amdgcn_mfma_f32_16x16x32_bf16(a1, bf1[nt], acc[mt][nt], 0, 0, 0);
      }
    }

    float pv[3];
#pragma unroll
    for (int nt = 0; nt < 3; nt++) {
      float p = 0.f;
#pragma unroll
      for (int mt = 0; mt < 3; mt++) {
        short4 s = *(const short4*)&arg[(nt * 3 + mt) * 256 + lane * 4];
        p += bf2f((u16)s.x) * acc[mt][nt][0] + bf2f((u16)s.y) * acc[mt][nt][1]
           + bf2f((u16)s.z) * acc[mt][nt][2] + bf2f((u16)s.w) * acc[mt][nt][3];
      }
      p += __shfl_xor(p, 16);
      p += __shfl_xor(p, 32);
      pv[nt] = p;
    }

    if (lane < 48) {
      float a = (lane < 16) ? pv[0] : (lane < 32 ? pv[1] : pv[2]);
      a += pb;
      int ww = lane;
#pragma unroll
      for (int kh = -1; kh <= 1; kh++) {
        int ih = h + kh;
        if (ih < 0 || ih > 47) continue;
#pragma unroll
        for (int kw = -1; kw <= 1; kw++) {
          int jw = ww + kw;
          if (jw < 0 || jw > 47) continue;
          a += pw[(kh + 1) * 3 + (kw + 1)] * bf2f(vA[(vrow0 + ih) * 72 + jw]);
        }
      }
      yg[h * 48 + ww] = a;
    }
  }
}

// ---------------------------------------------------------------------------
extern "C" void kernel_launch(void* const* d_in, const int* in_sizes, int n_in,
                              void* d_out, int out_size, void* d_ws, size_t ws_size,
                              hipStream_t stream) {
  const float* x      = (const float*)d_in[0];
  const float* rcv_w  = (const float*)d_in[1];
  const float* rcv_b  = (const float*)d_in[2];
  const float* pe_w   = (const float*)d_in[3];
  const float* pe_b   = (const float*)d_in[4];
  const float* proj_w = (const float*)d_in[5];
  const float* proj_b = (const float*)d_in[6];
  float* out = (float*)d_out;

  char* ws = (char*)d_ws;
  float* rcv = (float*)ws;                         // 0           28,311,552 B
  u16*   arF = (u16*)(ws + 28311552);              // 7,077,888 B
  u16*   awF = (u16*)(ws + 35389440);              // 9,437,184 B
  u16*   xTh = (u16*)(ws + 44826624);              // 4,718,592 B
  float* y   = (float*)(ws + 49545216);            // 9,437,184 B
  u16*   Whr = (u16*)(ws + 58982400);              //   393,216 B
  u16*   Wlr = (u16*)(ws + 59375616);              //   393,216 B
  u16*   Whp = (u16*)(ws + 59768832);              //   131,072 B
  u16*   Wlp = (u16*)(ws + 59899904);              //   131,072 B (end ~60 MB)
  // yT aliases arF/awF (free after attn_main)
  u16*   yTh = arF;
  u16*   yTl = awF;

  prep_kernel<<<dim3(832), 256, 0, stream>>>(rcv_w, Whr, Wlr, proj_w, Whp, Wlp, x, xTh);
  gemm_mfma_kernel<false><<<dim3(72 * 12), 256, 0, stream>>>(Whr, Wlr, rcv_b, xTh, xTh, rcv, 768);
  scores_kernel<<<dim3(768), 256, 0, stream>>>(rcv, arF, awF);
  attn_main_kernel<<<dim3(2048), 256, 0, stream>>>(rcv, arF, awF, pe_w, pe_b, y);
  split_transpose_kernel<<<dim3(36, 4, 4), 256, 0, stream>>>(y, yTh, yTl);
  gemm_n64_kernel<<<dim3(576), 256, 0, stream>>>(Whp, Wlp, proj_b, yTh, yTl, out);
}

// Round 16
// 120.025 us; speedup vs baseline: 1.5256x; 1.5256x over previous
//
#include <hip/hip_runtime.h>

#define S_ 2304   // 48*48

typedef unsigned short u16;
typedef __attribute__((ext_vector_type(8))) short bf16x8;
typedef __attribute__((ext_vector_type(4))) float f32x4;

static __device__ __forceinline__ u16 f2bf(float x) {
  union { float f; unsigned u; } v; v.f = x;
  unsigned r = v.u + 0x7FFFu + ((v.u >> 16) & 1u);
  return (u16)(r >> 16);
}
static __device__ __forceinline__ float bf2f(u16 h) {
  union { unsigned u; float f; } v; v.u = ((unsigned)h) << 16; return v.f;
}
static __device__ __forceinline__ float bflo(unsigned p) {
  union { unsigned u; float f; } v; v.u = p << 16; return v.f;
}
static __device__ __forceinline__ float bfhi(unsigned p) {
  union { unsigned u; float f; } v; v.u = p & 0xFFFF0000u; return v.f;
}

// ---------------------------------------------------------------------------
// Prep: weight split (blocks 0..255) + x split-transpose h-only (256..831).
// ---------------------------------------------------------------------------
__global__ __launch_bounds__(256) void prep_kernel(
    const float* __restrict__ w0, u16* __restrict__ wh0, u16* __restrict__ wl0,
    const float* __restrict__ w1, u16* __restrict__ wh1, u16* __restrict__ wl1,
    const float* __restrict__ x, u16* __restrict__ xTh)
{
  __shared__ u16 tile[64][65];
  const int bid = blockIdx.x;
  const int tid = threadIdx.x;
  if (bid < 256) {
    const float* w; u16 *wh, *wl; int id;
    if (bid < 192) { w = w0; wh = wh0; wl = wl0; id = bid * 256 + tid; }
    else { w = w1; wh = wh1; wl = wl1; id = (bid - 192) * 256 + tid; }
    float4 v = ((const float4*)w)[id];
    short4 h, l;
    float f[4] = {v.x, v.y, v.z, v.w};
    u16 hh[4], ll[4];
#pragma unroll
    for (int q = 0; q < 4; q++) {
      hh[q] = f2bf(f[q]);
      ll[q] = f2bf(f[q] - bf2f(hh[q]));
    }
    h.x = hh[0]; h.y = hh[1]; h.z = hh[2]; h.w = hh[3];
    l.x = ll[0]; l.y = ll[1]; l.z = ll[2]; l.w = ll[3];
    ((short4*)wh)[id] = h;
    ((short4*)wl)[id] = l;
    return;
  }
  const int bid2 = bid - 256;
  const int s0 = (bid2 % 36) * 64, c0 = ((bid2 / 36) % 4) * 64, b = bid2 / 144;
  const float* inb = x + (size_t)b * 256 * S_;
  u16* oh = xTh + (size_t)b * S_ * 256;
#pragma unroll
  for (int it = 0; it < 4; it++) {
    int id = tid + it * 256;
    int c = id >> 4, s4 = (id & 15) * 4;
    float4 v = *(const float4*)&inb[(size_t)(c0 + c) * S_ + s0 + s4];
    tile[s4 + 0][c] = f2bf(v.x);
    tile[s4 + 1][c] = f2bf(v.y);
    tile[s4 + 2][c] = f2bf(v.z);
    tile[s4 + 3][c] = f2bf(v.w);
  }
  __syncthreads();
#pragma unroll
  for (int it = 0; it < 4; it++) {
    int id = tid + it * 256;
    int s = id >> 4, c4 = (id & 15) * 4;
    short4 h;
    h.x = (short)tile[s][c4 + 0]; h.y = (short)tile[s][c4 + 1];
    h.z = (short)tile[s][c4 + 2]; h.w = (short)tile[s][c4 + 3];
    *(short4*)&oh[(size_t)(s0 + s) * 256 + c0 + c4] = h;
  }
}

// ---------------------------------------------------------------------------
// Split-transpose (h+l) for y before proj. Grid (36,4,4).
// ---------------------------------------------------------------------------
__global__ __launch_bounds__(256) void split_transpose_kernel(
    const float* __restrict__ in, u16* __restrict__ outh, u16* __restrict__ outl)
{
  __shared__ unsigned tile[64][65];
  const int s0 = blockIdx.x * 64, c0 = blockIdx.y * 64, b = blockIdx.z;
  const float* inb = in + (size_t)b * 256 * S_;
  u16* oh = outh + (size_t)b * S_ * 256;
  u16* ol = outl + (size_t)b * S_ * 256;
  const int tid = threadIdx.x;
#pragma unroll
  for (int it = 0; it < 4; it++) {
    int id = tid + it * 256;
    int c = id >> 4, s4 = (id & 15) * 4;
    float4 v = *(const float4*)&inb[(size_t)(c0 + c) * S_ + s0 + s4];
    float f[4] = {v.x, v.y, v.z, v.w};
#pragma unroll
    for (int q = 0; q < 4; q++) {
      u16 h = f2bf(f[q]);
      u16 l = f2bf(f[q] - bf2f(h));
      tile[s4 + q][c] = (unsigned)h | ((unsigned)l << 16);
    }
  }
  __syncthreads();
#pragma unroll
  for (int it = 0; it < 4; it++) {
    int id = tid + it * 256;
    int s = id >> 4, c4 = (id & 15) * 4;
    short4 h, l;
    unsigned p0 = tile[s][c4 + 0], p1 = tile[s][c4 + 1];
    unsigned p2 = tile[s][c4 + 2], p3 = tile[s][c4 + 3];
    h.x = (short)(p0 & 0xffff); h.y = (short)(p1 & 0xffff);
    h.z = (short)(p2 & 0xffff); h.w = (short)(p3 & 0xffff);
    l.x = (short)(p0 >> 16); l.y = (short)(p1 >> 16);
    l.z = (short)(p2 >> 16); l.w = (short)(p3 >> 16);
    *(short4*)&oh[(size_t)(s0 + s) * 256 + c0 + c4] = h;
    *(short4*)&ol[(size_t)(s0 + s) * 256 + c0 + c4] = l;
  }
}

// ---------------------------------------------------------------------------
// MFMA split-bf16 GEMM (r10 form), XLO=false: Out=(Wh+Wl)*Xh. BM=64 BN=128.
// ---------------------------------------------------------------------------
template <bool XLO>
__global__ __launch_bounds__(256) void gemm_mfma_kernel(
    const u16* __restrict__ Wh, const u16* __restrict__ Wl,
    const float* __restrict__ bias,
    const u16* __restrict__ XTh, const u16* __restrict__ XTl,
    float* __restrict__ Out, int M)
{
  __shared__ u16 wAh[2][64 * 40];
  __shared__ u16 wAl[2][64 * 40];
  const int MB = M >> 6;
  const int xcd = blockIdx.x & 7;
  const int idx = blockIdx.x >> 3;
  const int g = xcd * 9 + idx / MB;
  const int mb = idx % MB;
  const int nb = g % 18, b = g / 18;
  const int m0 = mb * 64, n0 = nb * 128;
  const int tid = threadIdx.x;
  const int wv = tid >> 6, lane = tid & 63;
  const int lr = lane & 15, lg = lane >> 4;
  const bf16x8 zv = {0, 0, 0, 0, 0, 0, 0, 0};

  const u16* xbh = XTh + ((size_t)b * S_ + n0 + wv * 32) * 256;
  const u16* xbl = XTl + ((size_t)b * S_ + n0 + wv * 32) * 256;

  f32x4 acc[4][2];
#pragma unroll
  for (int mt = 0; mt < 4; mt++)
#pragma unroll
    for (int nt = 0; nt < 2; nt++) acc[mt][nt] = (f32x4){0.f, 0.f, 0.f, 0.f};

#define STAGE_W(t, buf)                                                      \
  {                                                                          \
    _Pragma("unroll")                                                        \
    for (int r = 0; r < 2; r++) {                                            \
      int id = tid + r * 256;                                                \
      int m = id >> 3, k4 = (id & 7) * 4;                                    \
      *(short4*)&wAh[buf][m * 40 + k4] =                                     \
          *(const short4*)&Wh[(size_t)(m0 + m) * 256 + (t) * 32 + k4];       \
      *(short4*)&wAl[buf][m * 40 + k4] =                                     \
          *(const short4*)&Wl[(size_t)(m0 + m) * 256 + (t) * 32 + k4];       \
    }                                                                        \
  }

  STAGE_W(0, 0);
  bf16x8 cbh[2], cbl[2];
#pragma unroll
  for (int nt = 0; nt < 2; nt++) {
    size_t off = (size_t)(nt * 16 + lr) * 256 + lg * 8;
    cbh[nt] = *(const bf16x8*)&xbh[off];
    if (XLO) cbl[nt] = *(const bf16x8*)&xbl[off];
  }
  __syncthreads();

  for (int t = 0; t < 8; t++) {
    int buf = t & 1;
    if (t < 7) STAGE_W(t + 1, buf ^ 1);

    bf16x8 nbh[2], nbl[2];
    if (t < 7) {
#pragma unroll
      for (int nt = 0; nt < 2; nt++) {
        size_t off = (size_t)(nt * 16 + lr) * 256 + (t + 1) * 32 + lg * 8;
        nbh[nt] = *(const bf16x8*)&xbh[off];
        if (XLO) nbl[nt] = *(const bf16x8*)&xbl[off];
      }
    } else {
#pragma unroll
      for (int nt = 0; nt < 2; nt++) { nbh[nt] = zv; if (XLO) nbl[nt] = zv; }
    }

    bf16x8 ah[4], al[4];
#pragma unroll
    for (int mt = 0; mt < 4; mt++) {
      ah[mt] = *(const bf16x8*)&wAh[buf][(mt * 16 + lr) * 40 + lg * 8];
      al[mt] = *(const bf16x8*)&wAl[buf][(mt * 16 + lr) * 40 + lg * 8];
    }
#pragma unroll
    for (int mt = 0; mt < 4; mt++)
#pragma unroll
      for (int nt = 0; nt < 2; nt++) {
        acc[mt][nt] = __builtin_amdgcn_mfma_f32_16x16x32_bf16(ah[mt], cbh[nt], acc[mt][nt], 0, 0, 0);
        if (XLO)
          acc[mt][nt] = __builtin_amdgcn_mfma_f32_16x16x32_bf16(ah[mt], cbl[nt], acc[mt][nt], 0, 0, 0);
        acc[mt][nt] = __builtin_amdgcn_mfma_f32_16x16x32_bf16(al[mt], cbh[nt], acc[mt][nt], 0, 0, 0);
      }
    __syncthreads();
#pragma unroll
    for (int nt = 0; nt < 2; nt++) { cbh[nt] = nbh[nt]; if (XLO) cbl[nt] = nbl[nt]; }
  }

  float* ob = Out + (size_t)b * M * S_;
#pragma unroll
  for (int mt = 0; mt < 4; mt++) {
    float4 b4 = *(const float4*)&bias[m0 + mt * 16 + lg * 4];
    float bv[4] = {b4.x, b4.y, b4.z, b4.w};
#pragma unroll
    for (int nt = 0; nt < 2; nt++) {
      int s = n0 + wv * 32 + nt * 16 + lr;
#pragma unroll
      for (int r = 0; r < 4; r++) {
        int m = m0 + mt * 16 + lg * 4 + r;
        ob[(size_t)m * S_ + s] = acc[mt][nt][r] + bv[r];
      }
    }
  }
#undef STAGE_W
}

// ---------------------------------------------------------------------------
// Proj GEMM, BN=64 (576 blocks for occupancy). 3-term.
// ---------------------------------------------------------------------------
__global__ __launch_bounds__(256) void gemm_n64_kernel(
    const u16* __restrict__ Wh, const u16* __restrict__ Wl,
    const float* __restrict__ bias,
    const u16* __restrict__ XTh, const u16* __restrict__ XTl,
    float* __restrict__ Out)
{
  __shared__ u16 wAh[2][64 * 40];
  __shared__ u16 wAl[2][64 * 40];
  const int M = 256, MB = 4;
  const int xcd = blockIdx.x & 7;
  const int idx = blockIdx.x >> 3;
  const int g = xcd * 18 + idx / MB;
  const int mb = idx % MB;
  const int nb = g % 36, b = g / 36;
  const int m0 = mb * 64, n0 = nb * 64;
  const int tid = threadIdx.x;
  const int wv = tid >> 6, lane = tid & 63;
  const int wm = wv >> 1, wsd = wv & 1;
  const int lr = lane & 15, lg = lane >> 4;
  const bf16x8 zv = {0, 0, 0, 0, 0, 0, 0, 0};

  const u16* xbh = XTh + ((size_t)b * S_ + n0 + wsd * 32) * 256;
  const u16* xbl = XTl + ((size_t)b * S_ + n0 + wsd * 32) * 256;

  f32x4 acc[2][2];
#pragma unroll
  for (int mt = 0; mt < 2; mt++)
#pragma unroll
    for (int nt = 0; nt < 2; nt++) acc[mt][nt] = (f32x4){0.f, 0.f, 0.f, 0.f};

#define STAGE_W(t, buf)                                                      \
  {                                                                          \
    _Pragma("unroll")                                                        \
    for (int r = 0; r < 2; r++) {                                            \
      int id = tid + r * 256;                                                \
      int m = id >> 3, k4 = (id & 7) * 4;                                    \
      *(short4*)&wAh[buf][m * 40 + k4] =                                     \
          *(const short4*)&Wh[(size_t)(m0 + m) * 256 + (t) * 32 + k4];       \
      *(short4*)&wAl[buf][m * 40 + k4] =                                     \
          *(const short4*)&Wl[(size_t)(m0 + m) * 256 + (t) * 32 + k4];       \
    }                                                                        \
  }

  STAGE_W(0, 0);
  bf16x8 cbh[2], cbl[2];
#pragma unroll
  for (int nt = 0; nt < 2; nt++) {
    size_t off = (size_t)(nt * 16 + lr) * 256 + lg * 8;
    cbh[nt] = *(const bf16x8*)&xbh[off];
    cbl[nt] = *(const bf16x8*)&xbl[off];
  }
  __syncthreads();

  for (int t = 0; t < 8; t++) {
    int buf = t & 1;
    if (t < 7) STAGE_W(t + 1, buf ^ 1);

    bf16x8 nbh[2], nbl[2];
    if (t < 7) {
#pragma unroll
      for (int nt = 0; nt < 2; nt++) {
        size_t off = (size_t)(nt * 16 + lr) * 256 + (t + 1) * 32 + lg * 8;
        nbh[nt] = *(const bf16x8*)&xbh[off];
        nbl[nt] = *(const bf16x8*)&xbl[off];
      }
    } else {
#pragma unroll
      for (int nt = 0; nt < 2; nt++) { nbh[nt] = zv; nbl[nt] = zv; }
    }

    bf16x8 ah[2], al[2];
#pragma unroll
    for (int mt = 0; mt < 2; mt++) {
      ah[mt] = *(const bf16x8*)&wAh[buf][(wm * 32 + mt * 16 + lr) * 40 + lg * 8];
      al[mt] = *(const bf16x8*)&wAl[buf][(wm * 32 + mt * 16 + lr) * 40 + lg * 8];
    }
#pragma unroll
    for (int mt = 0; mt < 2; mt++)
#pragma unroll
      for (int nt = 0; nt < 2; nt++) {
        acc[mt][nt] = __builtin_amdgcn_mfma_f32_16x16x32_bf16(ah[mt], cbh[nt], acc[mt][nt], 0, 0, 0);
        acc[mt][nt] = __builtin_amdgcn_mfma_f32_16x16x32_bf16(ah[mt], cbl[nt], acc[mt][nt], 0, 0, 0);
        acc[mt][nt] = __builtin_amdgcn_mfma_f32_16x16x32_bf16(al[mt], cbh[nt], acc[mt][nt], 0, 0, 0);
      }
    __syncthreads();
#pragma unroll
    for (int nt = 0; nt < 2; nt++) { cbh[nt] = nbh[nt]; cbl[nt] = nbl[nt]; }
  }

  float* ob = Out + (size_t)b * M * S_;
#pragma unroll
  for (int mt = 0; mt < 2; mt++) {
    float4 b4 = *(const float4*)&bias[m0 + wm * 32 + mt * 16 + lg * 4];
    float bv[4] = {b4.x, b4.y, b4.z, b4.w};
#pragma unroll
    for (int nt = 0; nt < 2; nt++) {
      int s = n0 + wsd * 32 + nt * 16 + lr;
#pragma unroll
      for (int r = 0; r < 4; r++) {
        int m = m0 + wm * 32 + mt * 16 + lg * 4 + r;
        ob[(size_t)m * S_ + s] = acc[mt][nt][r] + bv[r];
      }
    }
  }
#undef STAGE_W
}

// ---------------------------------------------------------------------------
// Scores (r14 grid: 1024 blocks, 3 h each; 0..511 ROW, 512..1023 COL), with
// the phase chain halved: double-buffered Sm + operand tiles so each h is
//   [compute Sm[buf] + stage next ops] bar [reduce, exp stored into Sm] bar
//   [write, no trailing barrier]
// = 2 barriers/h (was 4), and exp computed ONCE (write just scales).
// ---------------------------------------------------------------------------
__global__ __launch_bounds__(256) void scores_kernel(
    const float* __restrict__ rcv, u16* __restrict__ arF, u16* __restrict__ awF)
{
  __shared__ float Sm[2][48 * 49];       // 18816 B (row S / col T, dbuf)
  __shared__ float red1[2][48];
  __shared__ unsigned rkp[2][8 * 48];    // row: packed rk pairs (dbuf)
  __shared__ float cq[2][16 * 48], ck[2][16 * 48];  // col staging (dbuf)
  const int bid = blockIdx.x;
  const int tid = threadIdx.x;

  if (bid < 512) {
    // ---------------- ROW ----------------
    const int hg = bid & 15, n = (bid >> 4) & 7, b = bid >> 7;
    const float* base = rcv + ((size_t)b * 768 + n * 96) * S_;   // rq; rk at +16*S_
    unsigned rqp[9][8];
#pragma unroll
    for (int k = 0; k < 9; k++) {
      int p = tid + k * 256;
#pragma unroll
      for (int d8 = 0; d8 < 8; d8++) {
        float v0 = base[(size_t)(2 * d8) * S_ + p];
        float v1 = base[(size_t)(2 * d8 + 1) * S_ + p];
        rqp[k][d8] = (unsigned)f2bf(v0) | ((unsigned)f2bf(v1) << 16);
      }
    }
    // prologue: stage rk for h0 into buf 0
    {
      int h = hg * 3;
      for (int id = tid; id < 384; id += 256) {
        int d8 = id / 48, w = id % 48;
        float v0 = base[(size_t)(16 + 2 * d8) * S_ + h * 48 + w];
        float v1 = base[(size_t)(16 + 2 * d8 + 1) * S_ + h * 48 + w];
        rkp[0][id] = (unsigned)f2bf(v0) | ((unsigned)f2bf(v1) << 16);
      }
    }
    __syncthreads();
    for (int hh = 0; hh < 3; hh++) {
      const int buf = hh & 1;
      const int h = hg * 3 + hh;
      // phase A: compute Sm[buf] + stage next-h rk into buf^1
#pragma unroll
      for (int k = 0; k < 9; k++) {
        int p = tid + k * 256;
        int i = p / 48, w = p % 48;
        float s = 0.f;
#pragma unroll
        for (int d8 = 0; d8 < 8; d8++) {
          unsigned a = rqp[k][d8], c = rkp[buf][d8 * 48 + w];
          s += bflo(a) * bflo(c) + bfhi(a) * bfhi(c);
        }
        Sm[buf][i * 49 + w] = s * 0.25f;
      }
      if (hh < 2) {
        int hn = h + 1;
        for (int id = tid; id < 384; id += 256) {
          int d8 = id / 48, w = id % 48;
          float v0 = base[(size_t)(16 + 2 * d8) * S_ + hn * 48 + w];
          float v1 = base[(size_t)(16 + 2 * d8 + 1) * S_ + hn * 48 + w];
          rkp[buf ^ 1][id] = (unsigned)f2bf(v0) | ((unsigned)f2bf(v1) << 16);
        }
      }
      __syncthreads();
      // phase B: reduce; store exp'd values back into Sm[buf]
      if (tid < 192) {
        int w = tid >> 2, e = tid & 3;
        float m = -1e30f;
        for (int i = e; i < 48; i += 4) m = fmaxf(m, Sm[buf][i * 49 + w]);
        m = fmaxf(m, __shfl_xor(m, 1));
        m = fmaxf(m, __shfl_xor(m, 2));
        float s = 0.f;
        for (int i = e; i < 48; i += 4) {
          float ev = __expf(Sm[buf][i * 49 + w] - m);
          Sm[buf][i * 49 + w] = ev;
          s += ev;
        }
        s += __shfl_xor(s, 1);
        s += __shfl_xor(s, 2);
        red1[buf][w] = 1.0f / s;
      }
      __syncthreads();
      // phase C: write (no trailing barrier; next compute uses buf^1)
      u16* dst = arF + ((size_t)(b * 8 + n) * 48 + h) * 2304;
      for (int id = tid; id < 576; id += 256) {
        int nt = id / 192, rem = id % 192, mt = rem / 64, l = rem % 64;
        int w = nt * 16 + (l & 15);
        int i0 = mt * 16 + ((l >> 4) << 2);
        float rs = red1[buf][w];
        short4 o;
        o.x = (short)f2bf(Sm[buf][(i0 + 0) * 49 + w] * rs);
        o.y = (short)f2bf(Sm[buf][(i0 + 1) * 49 + w] * rs);
        o.z = (short)f2bf(Sm[buf][(i0 + 2) * 49 + w] * rs);
        o.w = (short)f2bf(Sm[buf][(i0 + 3) * 49 + w] * rs);
        *(short4*)&dst[id * 4] = o;
      }
    }
  } else {
    // ---------------- COL ----------------
    const int bid2 = bid - 512;
    const int hg = bid2 & 15, n = (bid2 >> 4) & 7, b = bid2 >> 7;
    const float* base = rcv + ((size_t)b * 768 + n * 96 + 32) * S_;  // cq; ck +16*S_
    // prologue: stage cq/ck for h0 into buf 0
    {
      int h = hg * 3;
      for (int id = tid; id < 768; id += 256) {
        int d = id / 48, j = id % 48;
        cq[0][id] = base[(size_t)d * S_ + h * 48 + j];
        ck[0][id] = base[(size_t)(16 + d) * S_ + h * 48 + j];
      }
    }
    __syncthreads();
    for (int hh = 0; hh < 3; hh++) {
      const int buf = hh & 1;
      const int h = hg * 3 + hh;
      // phase A: compute Tm[buf] + stage next-h cq/ck into buf^1
      for (int id = tid; id < 2304; id += 256) {
        int w = id / 48, j = id % 48;
        float t = 0.f;
#pragma unroll
        for (int d = 0; d < 16; d++)
          t += ck[buf][d * 48 + w] * cq[buf][d * 48 + j];
        Sm[buf][w * 49 + j] = t * 0.25f;
      }
      if (hh < 2) {
        int hn = h + 1;
        for (int id = tid; id < 768; id += 256) {
          int d = id / 48, j = id % 48;
          cq[buf ^ 1][id] = base[(size_t)d * S_ + hn * 48 + j];
          ck[buf ^ 1][id] = base[(size_t)(16 + d) * S_ + hn * 48 + j];
        }
      }
      __syncthreads();
      // phase B: reduce; store exp'd values back
      if (tid < 192) {
        int w = tid >> 2, e = tid & 3;
        float m = -1e30f;
        for (int j = e; j < 48; j += 4) m = fmaxf(m, Sm[buf][w * 49 + j]);
        m = fmaxf(m, __shfl_xor(m, 1));
        m = fmaxf(m, __shfl_xor(m, 2));
        float s = 0.f;
        for (int j = e; j < 48; j += 4) {
          float ev = __expf(Sm[buf][w * 49 + j] - m);
          Sm[buf][w * 49 + j] = ev;
          s += ev;
        }
        s += __shfl_xor(s, 1);
        s += __shfl_xor(s, 2);
        red1[buf][w] = 1.0f / s;
      }
      __syncthreads();
      // phase C: write (no trailing barrier)
      u16* dst = awF + ((size_t)(b * 8 + n) * 48 + h) * 3072;
      for (int id = tid; id < 384; id += 256) {
        int nt = id / 128, rem = id % 128, ks = rem / 64, l = rem % 64;
        int w = nt * 16 + (l & 15);
        int j0 = ks * 32 + ((l >> 4) << 3);
        float rs = red1[buf][w];
        u16 t8[8];
#pragma unroll
        for (int e = 0; e < 8; e++) {
          int j = j0 + e;
          t8[e] = (j < 48) ? f2bf(Sm[buf][w * 49 + j] * rs) : (u16)0;
        }
        short4 o0, o1;
        o0.x = (short)t8[0]; o0.y = (short)t8[1]; o0.z = (short)t8[2]; o0.w = (short)t8[3];
        o1.x = (short)t8[4]; o1.y = (short)t8[5]; o1.z = (short)t8[6]; o1.w = (short)t8[7];
        *(short4*)&dst[id * 8]     = o0;
        *(short4*)&dst[id * 8 + 4] = o1;
      }
    }
  }
}

// ---------------------------------------------------------------------------
// Main contraction + PE conv (verbatim r14 body).
// ---------------------------------------------------------------------------
__global__ __launch_bounds__(256) void attn_main_kernel(
    const float* __restrict__ rcv, const u16* __restrict__ arF,
    const u16* __restrict__ awF, const float* __restrict__ pe_w,
    const float* __restrict__ pe_b, float* __restrict__ y)
{
  __shared__ u16 vA[96 * 72];         // 13824 B
  const int id0 = blockIdx.x;
  const int n = id0 & 7;              // XCD swizzle
  const int rest = id0 >> 3;          // 0..255
  const int b = rest >> 6;
  const int inner = rest & 63;
  const int dchunk = inner >> 2;      // 0..15 (2 planes each)
  const int hc = inner & 3;
  const int tid = threadIdx.x;
  const int wave = tid >> 6, lane = tid & 63;
  const int dl = wave >> 1, half = wave & 1;
  const int h0 = hc * 12 + half * 6;
  const int lr = lane & 15, lg = lane >> 4;

  for (int id = tid; id < 96 * 24; id += 256) {
    int row = id / 24, col = 48 + id % 24;
    vA[row * 72 + col] = 0;
  }
  const float* vbase = rcv + ((size_t)b * 768 + n * 96 + 64 + dchunk * 2) * S_;
  for (int id = tid; id < 1152; id += 256) {
    int dl2 = id / 576, rem = id % 576;
    int i = rem / 12, j4 = (rem % 12) * 4;
    float4 v = *(const float4*)&vbase[(size_t)dl2 * S_ + i * 48 + j4];
    short4 s;
    s.x = (short)f2bf(v.x); s.y = (short)f2bf(v.y);
    s.z = (short)f2bf(v.z); s.w = (short)f2bf(v.w);
    *(short4*)&vA[(dl2 * 48 + i) * 72 + j4] = s;
  }
  __syncthreads();   // the only barrier

  const size_t bn48 = (size_t)(b * 8 + n) * 48;
  const int c = n * 32 + dchunk * 2 + dl;
  float pw[9];
#pragma unroll
  for (int t = 0; t < 9; t++) pw[t] = pe_w[c * 9 + t];
  const float pb = pe_b[c];
  float* yg = y + ((size_t)b * 256 + c) * S_;
  const int vrow0 = dl * 48;

  for (int hh = 0; hh < 6; hh++) {
    int h = h0 + hh;
    const u16* awg = awF + (bn48 + h) * 3072;
    const u16* arg = arF + (bn48 + h) * 2304;

    bf16x8 bf0[3], bf1[3];
#pragma unroll
    for (int nt = 0; nt < 3; nt++) {
      bf0[nt] = *(const bf16x8*)&awg[nt * 1024 + lane * 8];
      bf1[nt] = *(const bf16x8*)&awg[nt * 1024 + 512 + lane * 8];
    }

    f32x4 acc[3][3];
#pragma unroll
    for (int mt = 0; mt < 3; mt++)
#pragma unroll
      for (int nt = 0; nt < 3; nt++) acc[mt][nt] = (f32x4){0.f, 0.f, 0.f, 0.f};

#pragma unroll
    for (int mt = 0; mt < 3; mt++) {
      bf16x8 a0 = *(const bf16x8*)&vA[(vrow0 + mt * 16 + lr) * 72 + lg * 8];
      bf16x8 a1 = *(const bf16x8*)&vA[(vrow0 + mt * 16 + lr) * 72 + 32 + lg * 8];
#pragma unroll
      for (int nt = 0; nt < 3; nt++) {
        acc[mt][nt] = __builtin_amdgcn_mfma_f32_16x16x32_bf16(a0, bf0[nt], acc[mt][nt], 0, 0, 0);
        acc[mt][nt] = __builtin_amdgcn_mfma_f32_16x16x32_bf16(a1, bf1[nt], acc[mt][nt], 0, 0, 0);
      }
    }

    float pv[3];
#pragma unroll
    for (int nt = 0; nt < 3; nt++) {
      float p = 0.f;
#pragma unroll
      for (int mt = 0; mt < 3; mt++) {
        short4 s = *(const short4*)&arg[(nt * 3 + mt) * 256 + lane * 4];
        p += bf2f((u16)s.x) * acc[mt][nt][0] + bf2f((u16)s.y) * acc[mt][nt][1]
           + bf2f((u16)s.z) * acc[mt][nt][2] + bf2f((u16)s.w) * acc[mt][nt][3];
      }
      p += __shfl_xor(p, 16);
      p += __shfl_xor(p, 32);
      pv[nt] = p;
    }

    if (lane < 48) {
      float a = (lane < 16) ? pv[0] : (lane < 32 ? pv[1] : pv[2]);
      a += pb;
      int ww = lane;
#pragma unroll
      for (int kh = -1; kh <= 1; kh++) {
        int ih = h + kh;
        if (ih < 0 || ih > 47) continue;
#pragma unroll
        for (int kw = -1; kw <= 1; kw++) {
          int jw = ww + kw;
          if (jw < 0 || jw > 47) continue;
          a += pw[(kh + 1) * 3 + (kw + 1)] * bf2f(vA[(vrow0 + ih) * 72 + jw]);
        }
      }
      yg[h * 48 + ww] = a;
    }
  }
}

// ---------------------------------------------------------------------------
extern "C" void kernel_launch(void* const* d_in, const int* in_sizes, int n_in,
                              void* d_out, int out_size, void* d_ws, size_t ws_size,
                              hipStream_t stream) {
  const float* x      = (const float*)d_in[0];
  const float* rcv_w  = (const float*)d_in[1];
  const float* rcv_b  = (const float*)d_in[2];
  const float* pe_w   = (const float*)d_in[3];
  const float* pe_b   = (const float*)d_in[4];
  const float* proj_w = (const float*)d_in[5];
  const float* proj_b = (const float*)d_in[6];
  float* out = (float*)d_out;

  char* ws = (char*)d_ws;
  float* rcv = (float*)ws;                         // 0           28,311,552 B
  u16*   arF = (u16*)(ws + 28311552);              // 7,077,888 B
  u16*   awF = (u16*)(ws + 35389440);              // 9,437,184 B
  u16*   xTh = (u16*)(ws + 44826624);              // 4,718,592 B
  float* y   = (float*)(ws + 49545216);            // 9,437,184 B
  u16*   Whr = (u16*)(ws + 58982400);              //   393,216 B
  u16*   Wlr = (u16*)(ws + 59375616);              //   393,216 B
  u16*   Whp = (u16*)(ws + 59768832);              //   131,072 B
  u16*   Wlp = (u16*)(ws + 59899904);              //   131,072 B (end ~60 MB)
  // yT aliases arF/awF (free after attn_main)
  u16*   yTh = arF;
  u16*   yTl = awF;

  prep_kernel<<<dim3(832), 256, 0, stream>>>(rcv_w, Whr, Wlr, proj_w, Whp, Wlp, x, xTh);
  gemm_mfma_kernel<false><<<dim3(72 * 12), 256, 0, stream>>>(Whr, Wlr, rcv_b, xTh, xTh, rcv, 768);
  scores_kernel<<<dim3(1024), 256, 0, stream>>>(rcv, arF, awF);
  attn_main_kernel<<<dim3(2048), 256, 0, stream>>>(rcv, arF, awF, pe_w, pe_b, y);
  split_transpose_kernel<<<dim3(36, 4, 4), 256, 0, stream>>>(y, yTh, yTl);
  gemm_n64_kernel<<<dim3(576), 256, 0, stream>>>(Whp, Wlp, proj_b, yTh, yTl, out);
}

// Round 18
// 113.124 us; speedup vs baseline: 1.6187x; 1.0610x over previous
//
#include <hip/hip_runtime.h>

#define S_ 2304   // 48*48

typedef unsigned short u16;
typedef unsigned int u32;
typedef __attribute__((ext_vector_type(8))) short bf16x8;
typedef __attribute__((ext_vector_type(4))) float f32x4;

static __device__ __forceinline__ u16 f2bf(float x) {
  union { float f; unsigned u; } v; v.f = x;
  unsigned r = v.u + 0x7FFFu + ((v.u >> 16) & 1u);
  return (u16)(r >> 16);
}
static __device__ __forceinline__ float bf2f(u16 h) {
  union { unsigned u; float f; } v; v.u = ((unsigned)h) << 16; return v.f;
}
static __device__ __forceinline__ float bflo(unsigned p) {
  union { unsigned u; float f; } v; v.u = p << 16; return v.f;
}
static __device__ __forceinline__ float bfhi(unsigned p) {
  union { unsigned u; float f; } v; v.u = p & 0xFFFF0000u; return v.f;
}

// ---------------------------------------------------------------------------
// Prep: weight split (blocks 0..255) + x split-transpose h-only (256..831).
// ---------------------------------------------------------------------------
__global__ __launch_bounds__(256) void prep_kernel(
    const float* __restrict__ w0, u16* __restrict__ wh0, u16* __restrict__ wl0,
    const float* __restrict__ w1, u16* __restrict__ wh1, u16* __restrict__ wl1,
    const float* __restrict__ x, u16* __restrict__ xTh)
{
  __shared__ u16 tile[64][65];
  const int bid = blockIdx.x;
  const int tid = threadIdx.x;
  if (bid < 256) {
    const float* w; u16 *wh, *wl; int id;
    if (bid < 192) { w = w0; wh = wh0; wl = wl0; id = bid * 256 + tid; }
    else { w = w1; wh = wh1; wl = wl1; id = (bid - 192) * 256 + tid; }
    float4 v = ((const float4*)w)[id];
    short4 h, l;
    float f[4] = {v.x, v.y, v.z, v.w};
    u16 hh[4], ll[4];
#pragma unroll
    for (int q = 0; q < 4; q++) {
      hh[q] = f2bf(f[q]);
      ll[q] = f2bf(f[q] - bf2f(hh[q]));
    }
    h.x = hh[0]; h.y = hh[1]; h.z = hh[2]; h.w = hh[3];
    l.x = ll[0]; l.y = ll[1]; l.z = ll[2]; l.w = ll[3];
    ((short4*)wh)[id] = h;
    ((short4*)wl)[id] = l;
    return;
  }
  const int bid2 = bid - 256;
  const int s0 = (bid2 % 36) * 64, c0 = ((bid2 / 36) % 4) * 64, b = bid2 / 144;
  const float* inb = x + (size_t)b * 256 * S_;
  u16* oh = xTh + (size_t)b * S_ * 256;
#pragma unroll
  for (int it = 0; it < 4; it++) {
    int id = tid + it * 256;
    int c = id >> 4, s4 = (id & 15) * 4;
    float4 v = *(const float4*)&inb[(size_t)(c0 + c) * S_ + s0 + s4];
    tile[s4 + 0][c] = f2bf(v.x);
    tile[s4 + 1][c] = f2bf(v.y);
    tile[s4 + 2][c] = f2bf(v.z);
    tile[s4 + 3][c] = f2bf(v.w);
  }
  __syncthreads();
#pragma unroll
  for (int it = 0; it < 4; it++) {
    int id = tid + it * 256;
    int s = id >> 4, c4 = (id & 15) * 4;
    short4 h;
    h.x = (short)tile[s][c4 + 0]; h.y = (short)tile[s][c4 + 1];
    h.z = (short)tile[s][c4 + 2]; h.w = (short)tile[s][c4 + 3];
    *(short4*)&oh[(size_t)(s0 + s) * 256 + c0 + c4] = h;
  }
}

// ---------------------------------------------------------------------------
// Split-transpose (h+l) for y before proj. Grid (36,4,4).
// ---------------------------------------------------------------------------
__global__ __launch_bounds__(256) void split_transpose_kernel(
    const float* __restrict__ in, u16* __restrict__ outh, u16* __restrict__ outl)
{
  __shared__ unsigned tile[64][65];
  const int s0 = blockIdx.x * 64, c0 = blockIdx.y * 64, b = blockIdx.z;
  const float* inb = in + (size_t)b * 256 * S_;
  u16* oh = outh + (size_t)b * S_ * 256;
  u16* ol = outl + (size_t)b * S_ * 256;
  const int tid = threadIdx.x;
#pragma unroll
  for (int it = 0; it < 4; it++) {
    int id = tid + it * 256;
    int c = id >> 4, s4 = (id & 15) * 4;
    float4 v = *(const float4*)&inb[(size_t)(c0 + c) * S_ + s0 + s4];
    float f[4] = {v.x, v.y, v.z, v.w};
#pragma unroll
    for (int q = 0; q < 4; q++) {
      u16 h = f2bf(f[q]);
      u16 l = f2bf(f[q] - bf2f(h));
      tile[s4 + q][c] = (unsigned)h | ((unsigned)l << 16);
    }
  }
  __syncthreads();
#pragma unroll
  for (int it = 0; it < 4; it++) {
    int id = tid + it * 256;
    int s = id >> 4, c4 = (id & 15) * 4;
    short4 h, l;
    unsigned p0 = tile[s][c4 + 0], p1 = tile[s][c4 + 1];
    unsigned p2 = tile[s][c4 + 2], p3 = tile[s][c4 + 3];
    h.x = (short)(p0 & 0xffff); h.y = (short)(p1 & 0xffff);
    h.z = (short)(p2 & 0xffff); h.w = (short)(p3 & 0xffff);
    l.x = (short)(p0 >> 16); l.y = (short)(p1 >> 16);
    l.z = (short)(p2 >> 16); l.w = (short)(p3 >> 16);
    *(short4*)&oh[(size_t)(s0 + s) * 256 + c0 + c4] = h;
    *(short4*)&ol[(size_t)(s0 + s) * 256 + c0 + c4] = l;
  }
}

// ---------------------------------------------------------------------------
// MFMA split-bf16 GEMM for rcv: Out = (Wh+Wl)*Xh, M=768 fixed.
// Epilogue writes PAIR-PACKED bf16 (qkvP u32 = bf16(plane even)|bf16(odd)<<16)
// -- the D-fragment rows lg*4+r are 4 consecutive planes, so packing is
// thread-local. Layout: qkvP[(b*8+head)*48 + pp][s], pp = plane/2
// (rq pp0-7, rk 8-15, cq 16-23, ck 24-31, v 32-47).
// ---------------------------------------------------------------------------
__global__ __launch_bounds__(256) void gemm_mfma_kernel(
    const u16* __restrict__ Wh, const u16* __restrict__ Wl,
    const float* __restrict__ bias,
    const u16* __restrict__ XTh, u32* __restrict__ qkvP)
{
  __shared__ u16 wAh[2][64 * 40];
  __shared__ u16 wAl[2][64 * 40];
  const int MB = 12;
  const int xcd = blockIdx.x & 7;
  const int idx = blockIdx.x >> 3;
  const int g = xcd * 9 + idx / MB;
  const int mb = idx % MB;
  const int nb = g % 18, b = g / 18;
  const int m0 = mb * 64, n0 = nb * 128;
  const int tid = threadIdx.x;
  const int wv = tid >> 6, lane = tid & 63;
  const int lr = lane & 15, lg = lane >> 4;
  const bf16x8 zv = {0, 0, 0, 0, 0, 0, 0, 0};

  const u16* xbh = XTh + ((size_t)b * S_ + n0 + wv * 32) * 256;

  f32x4 acc[4][2];
#pragma unroll
  for (int mt = 0; mt < 4; mt++)
#pragma unroll
    for (int nt = 0; nt < 2; nt++) acc[mt][nt] = (f32x4){0.f, 0.f, 0.f, 0.f};

#define STAGE_W(t, buf)                                                      \
  {                                                                          \
    _Pragma("unroll")                                                        \
    for (int r = 0; r < 2; r++) {                                            \
      int id = tid + r * 256;                                                \
      int m = id >> 3, k4 = (id & 7) * 4;                                    \
      *(short4*)&wAh[buf][m * 40 + k4] =                                     \
          *(const short4*)&Wh[(size_t)(m0 + m) * 256 + (t) * 32 + k4];       \
      *(short4*)&wAl[buf][m * 40 + k4] =                                     \
          *(const short4*)&Wl[(size_t)(m0 + m) * 256 + (t) * 32 + k4];       \
    }                                                                        \
  }

  STAGE_W(0, 0);
  bf16x8 cbh[2];
#pragma unroll
  for (int nt = 0; nt < 2; nt++) {
    size_t off = (size_t)(nt * 16 + lr) * 256 + lg * 8;
    cbh[nt] = *(const bf16x8*)&xbh[off];
  }
  __syncthreads();

  for (int t = 0; t < 8; t++) {
    int buf = t & 1;
    if (t < 7) STAGE_W(t + 1, buf ^ 1);

    bf16x8 nbh[2];
    if (t < 7) {
#pragma unroll
      for (int nt = 0; nt < 2; nt++) {
        size_t off = (size_t)(nt * 16 + lr) * 256 + (t + 1) * 32 + lg * 8;
        nbh[nt] = *(const bf16x8*)&xbh[off];
      }
    } else {
#pragma unroll
      for (int nt = 0; nt < 2; nt++) nbh[nt] = zv;
    }

    bf16x8 ah[4], al[4];
#pragma unroll
    for (int mt = 0; mt < 4; mt++) {
      ah[mt] = *(const bf16x8*)&wAh[buf][(mt * 16 + lr) * 40 + lg * 8];
      al[mt] = *(const bf16x8*)&wAl[buf][(mt * 16 + lr) * 40 + lg * 8];
    }
#pragma unroll
    for (int mt = 0; mt < 4; mt++)
#pragma unroll
      for (int nt = 0; nt < 2; nt++) {
        acc[mt][nt] = __builtin_amdgcn_mfma_f32_16x16x32_bf16(ah[mt], cbh[nt], acc[mt][nt], 0, 0, 0);
        acc[mt][nt] = __builtin_amdgcn_mfma_f32_16x16x32_bf16(al[mt], cbh[nt], acc[mt][nt], 0, 0, 0);
      }
    __syncthreads();
#pragma unroll
    for (int nt = 0; nt < 2; nt++) cbh[nt] = nbh[nt];
  }

  // epilogue: pack pairs of consecutive planes into u32
#pragma unroll
  for (int mt = 0; mt < 4; mt++) {
    int mb_ = m0 + mt * 16 + lg * 4;       // 4 consecutive planes, 4-aligned
    float4 b4 = *(const float4*)&bias[mb_];
    int head = mb_ / 96, pl = mb_ % 96;    // never crosses a head boundary
    size_t rowoff = ((size_t)(b * 8 + head) * 48 + (pl >> 1)) * S_;
#pragma unroll
    for (int nt = 0; nt < 2; nt++) {
      int s = n0 + wv * 32 + nt * 16 + lr;
      u16 h0 = f2bf(acc[mt][nt][0] + b4.x);
      u16 h1 = f2bf(acc[mt][nt][1] + b4.y);
      u16 h2 = f2bf(acc[mt][nt][2] + b4.z);
      u16 h3 = f2bf(acc[mt][nt][3] + b4.w);
      qkvP[rowoff + s]      = (u32)h0 | ((u32)h1 << 16);
      qkvP[rowoff + S_ + s] = (u32)h2 | ((u32)h3 << 16);
    }
  }
#undef STAGE_W
}

// ---------------------------------------------------------------------------
// Proj GEMM, BN=64 (576 blocks for occupancy). 3-term. (unchanged)
// ---------------------------------------------------------------------------
__global__ __launch_bounds__(256) void gemm_n64_kernel(
    const u16* __restrict__ Wh, const u16* __restrict__ Wl,
    const float* __restrict__ bias,
    const u16* __restrict__ XTh, const u16* __restrict__ XTl,
    float* __restrict__ Out)
{
  __shared__ u16 wAh[2][64 * 40];
  __shared__ u16 wAl[2][64 * 40];
  const int M = 256, MB = 4;
  const int xcd = blockIdx.x & 7;
  const int idx = blockIdx.x >> 3;
  const int g = xcd * 18 + idx / MB;
  const int mb = idx % MB;
  const int nb = g % 36, b = g / 36;
  const int m0 = mb * 64, n0 = nb * 64;
  const int tid = threadIdx.x;
  const int wv = tid >> 6, lane = tid & 63;
  const int wm = wv >> 1, wsd = wv & 1;
  const int lr = lane & 15, lg = lane >> 4;
  const bf16x8 zv = {0, 0, 0, 0, 0, 0, 0, 0};

  const u16* xbh = XTh + ((size_t)b * S_ + n0 + wsd * 32) * 256;
  const u16* xbl = XTl + ((size_t)b * S_ + n0 + wsd * 32) * 256;

  f32x4 acc[2][2];
#pragma unroll
  for (int mt = 0; mt < 2; mt++)
#pragma unroll
    for (int nt = 0; nt < 2; nt++) acc[mt][nt] = (f32x4){0.f, 0.f, 0.f, 0.f};

#define STAGE_W(t, buf)                                                      \
  {                                                                          \
    _Pragma("unroll")                                                        \
    for (int r = 0; r < 2; r++) {                                            \
      int id = tid + r * 256;                                                \
      int m = id >> 3, k4 = (id & 7) * 4;                                    \
      *(short4*)&wAh[buf][m * 40 + k4] =                                     \
          *(const short4*)&Wh[(size_t)(m0 + m) * 256 + (t) * 32 + k4];       \
      *(short4*)&wAl[buf][m * 40 + k4] =                                     \
          *(const short4*)&Wl[(size_t)(m0 + m) * 256 + (t) * 32 + k4];       \
    }                                                                        \
  }

  STAGE_W(0, 0);
  bf16x8 cbh[2], cbl[2];
#pragma unroll
  for (int nt = 0; nt < 2; nt++) {
    size_t off = (size_t)(nt * 16 + lr) * 256 + lg * 8;
    cbh[nt] = *(const bf16x8*)&xbh[off];
    cbl[nt] = *(const bf16x8*)&xbl[off];
  }
  __syncthreads();

  for (int t = 0; t < 8; t++) {
    int buf = t & 1;
    if (t < 7) STAGE_W(t + 1, buf ^ 1);

    bf16x8 nbh[2], nbl[2];
    if (t < 7) {
#pragma unroll
      for (int nt = 0; nt < 2; nt++) {
        size_t off = (size_t)(nt * 16 + lr) * 256 + (t + 1) * 32 + lg * 8;
        nbh[nt] = *(const bf16x8*)&xbh[off];
        nbl[nt] = *(const bf16x8*)&xbl[off];
      }
    } else {
#pragma unroll
      for (int nt = 0; nt < 2; nt++) { nbh[nt] = zv; nbl[nt] = zv; }
    }

    bf16x8 ah[2], al[2];
#pragma unroll
    for (int mt = 0; mt < 2; mt++) {
      ah[mt] = *(const bf16x8*)&wAh[buf][(wm * 32 + mt * 16 + lr) * 40 + lg * 8];
      al[mt] = *(const bf16x8*)&wAl[buf][(wm * 32 + mt * 16 + lr) * 40 + lg * 8];
    }
#pragma unroll
    for (int mt = 0; mt < 2; mt++)
#pragma unroll
      for (int nt = 0; nt < 2; nt++) {
        acc[mt][nt] = __builtin_amdgcn_mfma_f32_16x16x32_bf16(ah[mt], cbh[nt], acc[mt][nt], 0, 0, 0);
        acc[mt][nt] = __builtin_amdgcn_mfma_f32_16x16x32_bf16(ah[mt], cbl[nt], acc[mt][nt], 0, 0, 0);
        acc[mt][nt] = __builtin_amdgcn_mfma_f32_16x16x32_bf16(al[mt], cbh[nt], acc[mt][nt], 0, 0, 0);
      }
    __syncthreads();
#pragma unroll
    for (int nt = 0; nt < 2; nt++) { cbh[nt] = nbh[nt]; cbl[nt] = nbl[nt]; }
  }

  float* ob = Out + (size_t)b * M * S_;
#pragma unroll
  for (int mt = 0; mt < 2; mt++) {
    float4 b4 = *(const float4*)&bias[m0 + wm * 32 + mt * 16 + lg * 4];
    float bv[4] = {b4.x, b4.y, b4.z, b4.w};
#pragma unroll
    for (int nt = 0; nt < 2; nt++) {
      int s = n0 + wsd * 32 + nt * 16 + lr;
#pragma unroll
      for (int r = 0; r < 4; r++) {
        int m = m0 + wm * 32 + mt * 16 + lg * 4 + r;
        ob[(size_t)m * S_ + s] = acc[mt][nt][r] + bv[r];
      }
    }
  }
#undef STAGE_W
}

// ---------------------------------------------------------------------------
// Scores (r16 dbuf structure), all operands read as PACKED u32 pairs from
// qkvP -- no f2bf packing VALU, halved reads, col compute 8 packed iters.
// 1024 blocks: 0..511 ROW (rq pp0-7, rk pp8-15), 512..1023 COL (cq 16-23,
// ck 24-31).
// ---------------------------------------------------------------------------
__global__ __launch_bounds__(256) void scores_kernel(
    const u32* __restrict__ qkv, u16* __restrict__ arF, u16* __restrict__ awF)
{
  __shared__ float Sm[2][48 * 49];
  __shared__ float red1[2][48];
  __shared__ u32 rkp[2][8 * 48];
  __shared__ u32 cqp[2][8 * 48], ckp[2][8 * 48];
  const int bid = blockIdx.x;
  const int tid = threadIdx.x;

  if (bid < 512) {
    // ---------------- ROW ----------------
    const int hg = bid & 15, n = (bid >> 4) & 7, b = bid >> 7;
    const u32* base = qkv + (size_t)(b * 8 + n) * 48 * S_;
    u32 rqp[9][8];
#pragma unroll
    for (int k = 0; k < 9; k++) {
      int p = tid + k * 256;
#pragma unroll
      for (int d8 = 0; d8 < 8; d8++)
        rqp[k][d8] = base[(size_t)d8 * S_ + p];
    }
    {
      int h = hg * 3;
      for (int id = tid; id < 384; id += 256)
        rkp[0][id] = base[(size_t)(8 + id / 48) * S_ + h * 48 + (id % 48)];
    }
    __syncthreads();
    for (int hh = 0; hh < 3; hh++) {
      const int buf = hh & 1;
      const int h = hg * 3 + hh;
#pragma unroll
      for (int k = 0; k < 9; k++) {
        int p = tid + k * 256;
        int i = p / 48, w = p % 48;
        float s = 0.f;
#pragma unroll
        for (int d8 = 0; d8 < 8; d8++) {
          u32 a = rqp[k][d8], c = rkp[buf][d8 * 48 + w];
          s += bflo(a) * bflo(c) + bfhi(a) * bfhi(c);
        }
        Sm[buf][i * 49 + w] = s * 0.25f;
      }
      if (hh < 2) {
        int hn = h + 1;
        for (int id = tid; id < 384; id += 256)
          rkp[buf ^ 1][id] = base[(size_t)(8 + id / 48) * S_ + hn * 48 + (id % 48)];
      }
      __syncthreads();
      if (tid < 192) {
        int w = tid >> 2, e = tid & 3;
        float m = -1e30f;
        for (int i = e; i < 48; i += 4) m = fmaxf(m, Sm[buf][i * 49 + w]);
        m = fmaxf(m, __shfl_xor(m, 1));
        m = fmaxf(m, __shfl_xor(m, 2));
        float s = 0.f;
        for (int i = e; i < 48; i += 4) {
          float ev = __expf(Sm[buf][i * 49 + w] - m);
          Sm[buf][i * 49 + w] = ev;
          s += ev;
        }
        s += __shfl_xor(s, 1);
        s += __shfl_xor(s, 2);
        red1[buf][w] = 1.0f / s;
      }
      __syncthreads();
      u16* dst = arF + ((size_t)(b * 8 + n) * 48 + h) * 2304;
      for (int id = tid; id < 576; id += 256) {
        int nt = id / 192, rem = id % 192, mt = rem / 64, l = rem % 64;
        int w = nt * 16 + (l & 15);
        int i0 = mt * 16 + ((l >> 4) << 2);
        float rs = red1[buf][w];
        short4 o;
        o.x = (short)f2bf(Sm[buf][(i0 + 0) * 49 + w] * rs);
        o.y = (short)f2bf(Sm[buf][(i0 + 1) * 49 + w] * rs);
        o.z = (short)f2bf(Sm[buf][(i0 + 2) * 49 + w] * rs);
        o.w = (short)f2bf(Sm[buf][(i0 + 3) * 49 + w] * rs);
        *(short4*)&dst[id * 4] = o;
      }
    }
  } else {
    // ---------------- COL ----------------
    const int bid2 = bid - 512;
    const int hg = bid2 & 15, n = (bid2 >> 4) & 7, b = bid2 >> 7;
    const u32* base = qkv + (size_t)(b * 8 + n) * 48 * S_;
    {
      int h = hg * 3;
      for (int id = tid; id < 384; id += 256) {
        cqp[0][id] = base[(size_t)(16 + id / 48) * S_ + h * 48 + (id % 48)];
        ckp[0][id] = base[(size_t)(24 + id / 48) * S_ + h * 48 + (id % 48)];
      }
    }
    __syncthreads();
    for (int hh = 0; hh < 3; hh++) {
      const int buf = hh & 1;
      const int h = hg * 3 + hh;
      for (int id = tid; id < 2304; id += 256) {
        int w = id / 48, j = id % 48;
        float t = 0.f;
#pragma unroll
        for (int d8 = 0; d8 < 8; d8++) {
          u32 c = ckp[buf][d8 * 48 + w], a = cqp[buf][d8 * 48 + j];
          t += bflo(c) * bflo(a) + bfhi(c) * bfhi(a);
        }
        Sm[buf][w * 49 + j] = t * 0.25f;
      }
      if (hh < 2) {
        int hn = h + 1;
        for (int id = tid; id < 384; id += 256) {
          cqp[buf ^ 1][id] = base[(size_t)(16 + id / 48) * S_ + hn * 48 + (id % 48)];
          ckp[buf ^ 1][id] = base[(size_t)(24 + id / 48) * S_ + hn * 48 + (id % 48)];
        }
      }
      __syncthreads();
      if (tid < 192) {
        int w = tid >> 2, e = tid & 3;
        float m = -1e30f;
        for (int j = e; j < 48; j += 4) m = fmaxf(m, Sm[buf][w * 49 + j]);
        m = fmaxf(m, __shfl_xor(m, 1));
        m = fmaxf(m, __shfl_xor(m, 2));
        float s = 0.f;
        for (int j = e; j < 48; j += 4) {
          float ev = __expf(Sm[buf][w * 49 + j] - m);
          Sm[buf][w * 49 + j] = ev;
          s += ev;
        }
        s += __shfl_xor(s, 1);
        s += __shfl_xor(s, 2);
        red1[buf][w] = 1.0f / s;
      }
      __syncthreads();
      u16* dst = awF + ((size_t)(b * 8 + n) * 48 + h) * 3072;
      for (int id = tid; id < 384; id += 256) {
        int nt = id / 128, rem = id % 128, ks = rem / 64, l = rem % 64;
        int w = nt * 16 + (l & 15);
        int j0 = ks * 32 + ((l >> 4) << 3);
        float rs = red1[buf][w];
        u16 t8[8];
#pragma unroll
        for (int e = 0; e < 8; e++) {
          int j = j0 + e;
          t8[e] = (j < 48) ? f2bf(Sm[buf][w * 49 + j] * rs) : (u16)0;
        }
        short4 o0, o1;
        o0.x = (short)t8[0]; o0.y = (short)t8[1]; o0.z = (short)t8[2]; o0.w = (short)t8[3];
        o1.x = (short)t8[4]; o1.y = (short)t8[5]; o1.z = (short)t8[6]; o1.w = (short)t8[7];
        *(short4*)&dst[id * 8]     = o0;
        *(short4*)&dst[id * 8 + 4] = o1;
      }
    }
  }
}

// ---------------------------------------------------------------------------
// Main contraction + PE conv (r14 geometry); v staged from PACKED qkvP:
// uint4 loads, lo bf16 -> plane-even row, hi -> plane-odd row. No conversion.
// ---------------------------------------------------------------------------
__global__ __launch_bounds__(256) void attn_main_kernel(
    const u32* __restrict__ qkv, const u16* __restrict__ arF,
    const u16* __restrict__ awF, const float* __restrict__ pe_w,
    const float* __restrict__ pe_b, float* __restrict__ y)
{
  __shared__ u16 vA[96 * 72];         // 13824 B
  const int id0 = blockIdx.x;
  const int n = id0 & 7;              // XCD swizzle
  const int rest = id0 >> 3;          // 0..255
  const int b = rest >> 6;
  const int inner = rest & 63;
  const int dchunk = inner >> 2;      // 0..15 (one v-pair each)
  const int hc = inner & 3;
  const int tid = threadIdx.x;
  const int wave = tid >> 6, lane = tid & 63;
  const int dl = wave >> 1, half = wave & 1;
  const int h0 = hc * 12 + half * 6;
  const int lr = lane & 15, lg = lane >> 4;

  for (int id = tid; id < 96 * 24; id += 256) {
    int row = id / 24, col = 48 + id % 24;
    vA[row * 72 + col] = 0;
  }
  // v pair pp = 32 + dchunk; lo = plane dchunk*2 (dl=0), hi = plane +1 (dl=1)
  const u32* vrow = qkv + ((size_t)(b * 8 + n) * 48 + 32 + dchunk) * S_;
  for (int id = tid; id < 576; id += 256) {   // 2304 u32 / 4
    int i = id / 12, j4 = (id % 12) * 4;
    uint4 v = *(const uint4*)&vrow[i * 48 + j4];
    short4 lo, hi;
    lo.x = (short)(v.x & 0xffff); hi.x = (short)(v.x >> 16);
    lo.y = (short)(v.y & 0xffff); hi.y = (short)(v.y >> 16);
    lo.z = (short)(v.z & 0xffff); hi.z = (short)(v.z >> 16);
    lo.w = (short)(v.w & 0xffff); hi.w = (short)(v.w >> 16);
    *(short4*)&vA[i * 72 + j4] = lo;          // rows 0..47  (dl=0)
    *(short4*)&vA[(48 + i) * 72 + j4] = hi;   // rows 48..95 (dl=1)
  }
  __syncthreads();   // the only barrier

  const size_t bn48 = (size_t)(b * 8 + n) * 48;
  const int c = n * 32 + dchunk * 2 + dl;
  float pw[9];
#pragma unroll
  for (int t = 0; t < 9; t++) pw[t] = pe_w[c * 9 + t];
  const float pb = pe_b[c];
  float* yg = y + ((size_t)b * 256 + c) * S_;
  const int vrow0 = dl * 48;

  for (int hh = 0; hh < 6; hh++) {
    int h = h0 + hh;
    const u16* awg = awF + (bn48 + h) * 3072;
    const u16* arg = arF + (bn48 + h) * 2304;

    bf16x8 bf0[3], bf1[3];
#pragma unroll
    for (int nt = 0; nt < 3; nt++) {
      bf0[nt] = *(const bf16x8*)&awg[nt * 1024 + lane * 8];
      bf1[nt] = *(const bf16x8*)&awg[nt * 1024 + 512 + lane * 8];
    }

    f32x4 acc[3][3];
#pragma unroll
    for (int mt = 0; mt < 3; mt++)
#pragma unroll
      for (int nt = 0; nt < 3; nt++) acc[mt][nt] = (f32x4){0.f, 0.f, 0.f, 0.f};

#pragma unroll
    for (int mt = 0; mt < 3; mt++) {
      bf16x8 a0 = *(const bf16x8*)&vA[(vrow0 + mt * 16 + lr) * 72 + lg * 8];
      bf16x8 a1 = *(const bf16x8*)&vA[(vrow0 + mt * 16 + lr) * 72 + 32 + lg * 8];
#pragma unroll
      for (int nt = 0; nt < 3; nt++) {
        acc[mt][nt] = __builtin_amdgcn_mfma_f32_16x16x32_bf16(a0, bf0[nt], acc[mt][nt], 0, 0, 0);
        acc[mt][nt] = __builtin_amdgcn_mfma_f32_16x16x32_bf16(a1, bf1[nt], acc[mt][nt], 0, 0, 0);
      }
    }

    float pv[3];
#pragma unroll
    for (int nt = 0; nt < 3; nt++) {
      float p = 0.f;
#pragma unroll
      for (int mt = 0; mt < 3; mt++) {
        short4 s = *(const short4*)&arg[(nt * 3 + mt) * 256 + lane * 4];
        p += bf2f((u16)s.x) * acc[mt][nt][0] + bf2f((u16)s.y) * acc[mt][nt][1]
           + bf2f((u16)s.z) * acc[mt][nt][2] + bf2f((u16)s.w) * acc[mt][nt][3];
      }
      p += __shfl_xor(p, 16);
      p += __shfl_xor(p, 32);
      pv[nt] = p;
    }

    if (lane < 48) {
      float a = (lane < 16) ? pv[0] : (lane < 32 ? pv[1] : pv[2]);
      a += pb;
      int ww = lane;
#pragma unroll
      for (int kh = -1; kh <= 1; kh++) {
        int ih = h + kh;
        if (ih < 0 || ih > 47) continue;
#pragma unroll
        for (int kw = -1; kw <= 1; kw++) {
          int jw = ww + kw;
          if (jw < 0 || jw > 47) continue;
          a += pw[(kh + 1) * 3 + (kw + 1)] * bf2f(vA[(vrow0 + ih) * 72 + jw]);
        }
      }
      yg[h * 48 + ww] = a;
    }
  }
}

// ---------------------------------------------------------------------------
extern "C" void kernel_launch(void* const* d_in, const int* in_sizes, int n_in,
                              void* d_out, int out_size, void* d_ws, size_t ws_size,
                              hipStream_t stream) {
  const float* x      = (const float*)d_in[0];
  const float* rcv_w  = (const float*)d_in[1];
  const float* rcv_b  = (const float*)d_in[2];
  const float* pe_w   = (const float*)d_in[3];
  const float* pe_b   = (const float*)d_in[4];
  const float* proj_w = (const float*)d_in[5];
  const float* proj_b = (const float*)d_in[6];
  float* out = (float*)d_out;

  char* ws = (char*)d_ws;
  u32*   qkvP = (u32*)ws;                          // 0          14,155,776 B
  u16*   arF = (u16*)(ws + 14155776);              //  7,077,888 B
  u16*   awF = (u16*)(ws + 21233664);              //  9,437,184 B
  u16*   xTh = (u16*)(ws + 30670848);              //  4,718,592 B
  float* y   = (float*)(ws + 35389440);            //  9,437,184 B
  u16*   Whr = (u16*)(ws + 44826624);              //    393,216 B
  u16*   Wlr = (u16*)(ws + 45219840);              //    393,216 B
  u16*   Whp = (u16*)(ws + 45613056);              //    131,072 B
  u16*   Wlp = (u16*)(ws + 45744128);              //    131,072 B (end ~45.9 MB)
  // yT aliases arF/awF (free after attn_main)
  u16*   yTh = arF;
  u16*   yTl = awF;

  prep_kernel<<<dim3(832), 256, 0, stream>>>(rcv_w, Whr, Wlr, proj_w, Whp, Wlp, x, xTh);
  gemm_mfma_kernel<<<dim3(72 * 12), 256, 0, stream>>>(Whr, Wlr, rcv_b, xTh, qkvP);
  scores_kernel<<<dim3(1024), 256, 0, stream>>>(qkvP, arF, awF);
  attn_main_kernel<<<dim3(2048), 256, 0, stream>>>(qkvP, arF, awF, pe_w, pe_b, y);
  split_transpose_kernel<<<dim3(36, 4, 4), 256, 0, stream>>>(y, yTh, yTl);
  gemm_n64_kernel<<<dim3(576), 256, 0, stream>>>(Whp, Wlp, proj_b, yTh, yTl, out);
}

// Round 21
// 98.870 us; speedup vs baseline: 1.8520x; 1.1442x over previous
//
#include <hip/hip_runtime.h>

#define S_ 2304   // 48*48

typedef unsigned short u16;
typedef unsigned int u32;
typedef __attribute__((ext_vector_type(8))) short bf16x8;
typedef __attribute__((ext_vector_type(4))) float f32x4;

static __device__ __forceinline__ u16 f2bf(float x) {
  union { float f; unsigned u; } v; v.f = x;
  unsigned r = v.u + 0x7FFFu + ((v.u >> 16) & 1u);
  return (u16)(r >> 16);
}
static __device__ __forceinline__ float bf2f(u16 h) {
  union { unsigned u; float f; } v; v.u = ((unsigned)h) << 16; return v.f;
}
static __device__ __forceinline__ float bflo(unsigned p) {
  union { unsigned u; float f; } v; v.u = p << 16; return v.f;
}
static __device__ __forceinline__ float bfhi(unsigned p) {
  union { unsigned u; float f; } v; v.u = p & 0xFFFF0000u; return v.f;
}

// ---------------------------------------------------------------------------
// Prep: weight split (blocks 0..255) + x split-transpose h-only (256..831).
// ---------------------------------------------------------------------------
__global__ __launch_bounds__(256) void prep_kernel(
    const float* __restrict__ w0, u16* __restrict__ wh0, u16* __restrict__ wl0,
    const float* __restrict__ w1, u16* __restrict__ wh1, u16* __restrict__ wl1,
    const float* __restrict__ x, u16* __restrict__ xTh)
{
  __shared__ u16 tile[64][65];
  const int bid = blockIdx.x;
  const int tid = threadIdx.x;
  if (bid < 256) {
    const float* w; u16 *wh, *wl; int id;
    if (bid < 192) { w = w0; wh = wh0; wl = wl0; id = bid * 256 + tid; }
    else { w = w1; wh = wh1; wl = wl1; id = (bid - 192) * 256 + tid; }
    float4 v = ((const float4*)w)[id];
    short4 h, l;
    float f[4] = {v.x, v.y, v.z, v.w};
    u16 hh[4], ll[4];
#pragma unroll
    for (int q = 0; q < 4; q++) {
      hh[q] = f2bf(f[q]);
      ll[q] = f2bf(f[q] - bf2f(hh[q]));
    }
    h.x = hh[0]; h.y = hh[1]; h.z = hh[2]; h.w = hh[3];
    l.x = ll[0]; l.y = ll[1]; l.z = ll[2]; l.w = ll[3];
    ((short4*)wh)[id] = h;
    ((short4*)wl)[id] = l;
    return;
  }
  const int bid2 = bid - 256;
  const int s0 = (bid2 % 36) * 64, c0 = ((bid2 / 36) % 4) * 64, b = bid2 / 144;
  const float* inb = x + (size_t)b * 256 * S_;
  u16* oh = xTh + (size_t)b * S_ * 256;
#pragma unroll
  for (int it = 0; it < 4; it++) {
    int id = tid + it * 256;
    int c = id >> 4, s4 = (id & 15) * 4;
    float4 v = *(const float4*)&inb[(size_t)(c0 + c) * S_ + s0 + s4];
    tile[s4 + 0][c] = f2bf(v.x);
    tile[s4 + 1][c] = f2bf(v.y);
    tile[s4 + 2][c] = f2bf(v.z);
    tile[s4 + 3][c] = f2bf(v.w);
  }
  __syncthreads();
#pragma unroll
  for (int it = 0; it < 4; it++) {
    int id = tid + it * 256;
    int s = id >> 4, c4 = (id & 15) * 4;
    short4 h;
    h.x = (short)tile[s][c4 + 0]; h.y = (short)tile[s][c4 + 1];
    h.z = (short)tile[s][c4 + 2]; h.w = (short)tile[s][c4 + 3];
    *(short4*)&oh[(size_t)(s0 + s) * 256 + c0 + c4] = h;
  }
}

// ---------------------------------------------------------------------------
// MFMA split-bf16 GEMM for rcv: Out = (Wh+Wl)*Xh, M=768 fixed.
// Epilogue writes PAIR-PACKED bf16 qkvP (r18-proven).
// ---------------------------------------------------------------------------
__global__ __launch_bounds__(256) void gemm_mfma_kernel(
    const u16* __restrict__ Wh, const u16* __restrict__ Wl,
    const float* __restrict__ bias,
    const u16* __restrict__ XTh, u32* __restrict__ qkvP)
{
  __shared__ u16 wAh[2][64 * 40];
  __shared__ u16 wAl[2][64 * 40];
  const int MB = 12;
  const int xcd = blockIdx.x & 7;
  const int idx = blockIdx.x >> 3;
  const int g = xcd * 9 + idx / MB;
  const int mb = idx % MB;
  const int nb = g % 18, b = g / 18;
  const int m0 = mb * 64, n0 = nb * 128;
  const int tid = threadIdx.x;
  const int wv = tid >> 6, lane = tid & 63;
  const int lr = lane & 15, lg = lane >> 4;
  const bf16x8 zv = {0, 0, 0, 0, 0, 0, 0, 0};

  const u16* xbh = XTh + ((size_t)b * S_ + n0 + wv * 32) * 256;

  f32x4 acc[4][2];
#pragma unroll
  for (int mt = 0; mt < 4; mt++)
#pragma unroll
    for (int nt = 0; nt < 2; nt++) acc[mt][nt] = (f32x4){0.f, 0.f, 0.f, 0.f};

#define STAGE_W(t, buf)                                                      \
  {                                                                          \
    _Pragma("unroll")                                                        \
    for (int r = 0; r < 2; r++) {                                            \
      int id = tid + r * 256;                                                \
      int m = id >> 3, k4 = (id & 7) * 4;                                    \
      *(short4*)&wAh[buf][m * 40 + k4] =                                     \
          *(const short4*)&Wh[(size_t)(m0 + m) * 256 + (t) * 32 + k4];       \
      *(short4*)&wAl[buf][m * 40 + k4] =                                     \
          *(const short4*)&Wl[(size_t)(m0 + m) * 256 + (t) * 32 + k4];       \
    }                                                                        \
  }

  STAGE_W(0, 0);
  bf16x8 cbh[2];
#pragma unroll
  for (int nt = 0; nt < 2; nt++) {
    size_t off = (size_t)(nt * 16 + lr) * 256 + lg * 8;
    cbh[nt] = *(const bf16x8*)&xbh[off];
  }
  __syncthreads();

  for (int t = 0; t < 8; t++) {
    int buf = t & 1;
    if (t < 7) STAGE_W(t + 1, buf ^ 1);

    bf16x8 nbh[2];
    if (t < 7) {
#pragma unroll
      for (int nt = 0; nt < 2; nt++) {
        size_t off = (size_t)(nt * 16 + lr) * 256 + (t + 1) * 32 + lg * 8;
        nbh[nt] = *(const bf16x8*)&xbh[off];
      }
    } else {
#pragma unroll
      for (int nt = 0; nt < 2; nt++) nbh[nt] = zv;
    }

    bf16x8 ah[4], al[4];
#pragma unroll
    for (int mt = 0; mt < 4; mt++) {
      ah[mt] = *(const bf16x8*)&wAh[buf][(mt * 16 + lr) * 40 + lg * 8];
      al[mt] = *(const bf16x8*)&wAl[buf][(mt * 16 + lr) * 40 + lg * 8];
    }
#pragma unroll
    for (int mt = 0; mt < 4; mt++)
#pragma unroll
      for (int nt = 0; nt < 2; nt++) {
        acc[mt][nt] = __builtin_amdgcn_mfma_f32_16x16x32_bf16(ah[mt], cbh[nt], acc[mt][nt], 0, 0, 0);
        acc[mt][nt] = __builtin_amdgcn_mfma_f32_16x16x32_bf16(al[mt], cbh[nt], acc[mt][nt], 0, 0, 0);
      }
    __syncthreads();
#pragma unroll
    for (int nt = 0; nt < 2; nt++) cbh[nt] = nbh[nt];
  }

  // epilogue: pack pairs of consecutive planes into u32
#pragma unroll
  for (int mt = 0; mt < 4; mt++) {
    int mb_ = m0 + mt * 16 + lg * 4;
    float4 b4 = *(const float4*)&bias[mb_];
    int head = mb_ / 96, pl = mb_ % 96;
    size_t rowoff = ((size_t)(b * 8 + head) * 48 + (pl >> 1)) * S_;
#pragma unroll
    for (int nt = 0; nt < 2; nt++) {
      int s = n0 + wv * 32 + nt * 16 + lr;
      u16 h0 = f2bf(acc[mt][nt][0] + b4.x);
      u16 h1 = f2bf(acc[mt][nt][1] + b4.y);
      u16 h2 = f2bf(acc[mt][nt][2] + b4.z);
      u16 h3 = f2bf(acc[mt][nt][3] + b4.w);
      qkvP[rowoff + s]      = (u32)h0 | ((u32)h1 << 16);
      qkvP[rowoff + S_ + s] = (u32)h2 | ((u32)h3 << 16);
    }
  }
#undef STAGE_W
}

// ---------------------------------------------------------------------------
// Proj GEMM, BN=64, 576 blocks. B loaded DIRECTLY from packed yP [c][s]:
// per fragment element e, lane reads yP[(k0+lg*8+e)*S_+s] (each 16-lane
// group covers 64 contiguous bytes), unpacks h|l with bit ops. 3-term.
// kstep-ahead register prefetch retained. Replaces split_transpose+yT.
// ---------------------------------------------------------------------------
__global__ __launch_bounds__(256) void gemm_n64_kernel(
    const u16* __restrict__ Wh, const u16* __restrict__ Wl,
    const float* __restrict__ bias,
    const u32* __restrict__ yP, float* __restrict__ Out)
{
  __shared__ u16 wAh[2][64 * 40];
  __shared__ u16 wAl[2][64 * 40];
  const int M = 256, MB = 4;
  const int xcd = blockIdx.x & 7;
  const int idx = blockIdx.x >> 3;
  const int g = xcd * 18 + idx / MB;
  const int mb = idx % MB;
  const int nb = g % 36, b = g / 36;
  const int m0 = mb * 64, n0 = nb * 64;
  const int tid = threadIdx.x;
  const int wv = tid >> 6, lane = tid & 63;
  const int wm = wv >> 1, wsd = wv & 1;
  const int lr = lane & 15, lg = lane >> 4;

  const u32* yb = yP + (size_t)b * 256 * S_;
  const int s0 = n0 + wsd * 32;        // this wave's s-slice base

  f32x4 acc[2][2];
#pragma unroll
  for (int mt = 0; mt < 2; mt++)
#pragma unroll
    for (int nt = 0; nt < 2; nt++) acc[mt][nt] = (f32x4){0.f, 0.f, 0.f, 0.f};

#define STAGE_W(t, buf)                                                      \
  {                                                                          \
    _Pragma("unroll")                                                        \
    for (int r = 0; r < 2; r++) {                                            \
      int id = tid + r * 256;                                                \
      int m = id >> 3, k4 = (id & 7) * 4;                                    \
      *(short4*)&wAh[buf][m * 40 + k4] =                                     \
          *(const short4*)&Wh[(size_t)(m0 + m) * 256 + (t) * 32 + k4];       \
      *(short4*)&wAl[buf][m * 40 + k4] =                                     \
          *(const short4*)&Wl[(size_t)(m0 + m) * 256 + (t) * 32 + k4];       \
    }                                                                        \
  }

#define LOAD_B(t, dst)                                                       \
  {                                                                          \
    _Pragma("unroll")                                                        \
    for (int nt = 0; nt < 2; nt++) {                                         \
      int s = s0 + nt * 16 + lr;                                             \
      _Pragma("unroll")                                                      \
      for (int e = 0; e < 8; e++)                                            \
        dst[nt][e] = yb[(size_t)((t) * 32 + lg * 8 + e) * S_ + s];           \
    }                                                                        \
  }

  STAGE_W(0, 0);
  u32 cb[2][8];
  LOAD_B(0, cb);
  __syncthreads();

  for (int t = 0; t < 8; t++) {
    int buf = t & 1;
    if (t < 7) STAGE_W(t + 1, buf ^ 1);

    u32 nbv[2][8];
    if (t < 7) {
      LOAD_B(t + 1, nbv);
    } else {
#pragma unroll
      for (int nt = 0; nt < 2; nt++)
#pragma unroll
        for (int e = 0; e < 8; e++) nbv[nt][e] = 0;
    }

    bf16x8 ah[2], al[2];
#pragma unroll
    for (int mt = 0; mt < 2; mt++) {
      ah[mt] = *(const bf16x8*)&wAh[buf][(wm * 32 + mt * 16 + lr) * 40 + lg * 8];
      al[mt] = *(const bf16x8*)&wAl[buf][(wm * 32 + mt * 16 + lr) * 40 + lg * 8];
    }
    bf16x8 bh[2], bl[2];
#pragma unroll
    for (int nt = 0; nt < 2; nt++)
#pragma unroll
      for (int e = 0; e < 8; e++) {
        bh[nt][e] = (short)(cb[nt][e] & 0xffffu);
        bl[nt][e] = (short)(cb[nt][e] >> 16);
      }
#pragma unroll
    for (int mt = 0; mt < 2; mt++)
#pragma unroll
      for (int nt = 0; nt < 2; nt++) {
        acc[mt][nt] = __builtin_amdgcn_mfma_f32_16x16x32_bf16(ah[mt], bh[nt], acc[mt][nt], 0, 0, 0);
        acc[mt][nt] = __builtin_amdgcn_mfma_f32_16x16x32_bf16(ah[mt], bl[nt], acc[mt][nt], 0, 0, 0);
        acc[mt][nt] = __builtin_amdgcn_mfma_f32_16x16x32_bf16(al[mt], bh[nt], acc[mt][nt], 0, 0, 0);
      }
    __syncthreads();
#pragma unroll
    for (int nt = 0; nt < 2; nt++)
#pragma unroll
      for (int e = 0; e < 8; e++) cb[nt][e] = nbv[nt][e];
  }

  float* ob = Out + (size_t)b * M * S_;
#pragma unroll
  for (int mt = 0; mt < 2; mt++) {
    float4 b4 = *(const float4*)&bias[m0 + wm * 32 + mt * 16 + lg * 4];
    float bv[4] = {b4.x, b4.y, b4.z, b4.w};
#pragma unroll
    for (int nt = 0; nt < 2; nt++) {
      int s = n0 + wsd * 32 + nt * 16 + lr;
#pragma unroll
      for (int r = 0; r < 4; r++) {
        int m = m0 + wm * 32 + mt * 16 + lg * 4 + r;
        ob[(size_t)m * S_ + s] = acc[mt][nt][r] + bv[r];
      }
    }
  }
#undef STAGE_W
#undef LOAD_B
}

// ---------------------------------------------------------------------------
// Scores (r18-proven): packed u32 operands, dbuf, 1024 blocks.
// ---------------------------------------------------------------------------
__global__ __launch_bounds__(256) void scores_kernel(
    const u32* __restrict__ qkv, u16* __restrict__ arF, u16* __restrict__ awF)
{
  __shared__ float Sm[2][48 * 49];
  __shared__ float red1[2][48];
  __shared__ u32 rkp[2][8 * 48];
  __shared__ u32 cqp[2][8 * 48], ckp[2][8 * 48];
  const int bid = blockIdx.x;
  const int tid = threadIdx.x;

  if (bid < 512) {
    // ---------------- ROW ----------------
    const int hg = bid & 15, n = (bid >> 4) & 7, b = bid >> 7;
    const u32* base = qkv + (size_t)(b * 8 + n) * 48 * S_;
    u32 rqp[9][8];
#pragma unroll
    for (int k = 0; k < 9; k++) {
      int p = tid + k * 256;
#pragma unroll
      for (int d8 = 0; d8 < 8; d8++)
        rqp[k][d8] = base[(size_t)d8 * S_ + p];
    }
    {
      int h = hg * 3;
      for (int id = tid; id < 384; id += 256)
        rkp[0][id] = base[(size_t)(8 + id / 48) * S_ + h * 48 + (id % 48)];
    }
    __syncthreads();
    for (int hh = 0; hh < 3; hh++) {
      const int buf = hh & 1;
      const int h = hg * 3 + hh;
#pragma unroll
      for (int k = 0; k < 9; k++) {
        int p = tid + k * 256;
        int i = p / 48, w = p % 48;
        float s = 0.f;
#pragma unroll
        for (int d8 = 0; d8 < 8; d8++) {
          u32 a = rqp[k][d8], c = rkp[buf][d8 * 48 + w];
          s += bflo(a) * bflo(c) + bfhi(a) * bfhi(c);
        }
        Sm[buf][i * 49 + w] = s * 0.25f;
      }
      if (hh < 2) {
        int hn = h + 1;
        for (int id = tid; id < 384; id += 256)
          rkp[buf ^ 1][id] = base[(size_t)(8 + id / 48) * S_ + hn * 48 + (id % 48)];
      }
      __syncthreads();
      if (tid < 192) {
        int w = tid >> 2, e = tid & 3;
        float m = -1e30f;
        for (int i = e; i < 48; i += 4) m = fmaxf(m, Sm[buf][i * 49 + w]);
        m = fmaxf(m, __shfl_xor(m, 1));
        m = fmaxf(m, __shfl_xor(m, 2));
        float s = 0.f;
        for (int i = e; i < 48; i += 4) {
          float ev = __expf(Sm[buf][i * 49 + w] - m);
          Sm[buf][i * 49 + w] = ev;
          s += ev;
        }
        s += __shfl_xor(s, 1);
        s += __shfl_xor(s, 2);
        red1[buf][w] = 1.0f / s;
      }
      __syncthreads();
      u16* dst = arF + ((size_t)(b * 8 + n) * 48 + h) * 2304;
      for (int id = tid; id < 576; id += 256) {
        int nt = id / 192, rem = id % 192, mt = rem / 64, l = rem % 64;
        int w = nt * 16 + (l & 15);
        int i0 = mt * 16 + ((l >> 4) << 2);
        float rs = red1[buf][w];
        short4 o;
        o.x = (short)f2bf(Sm[buf][(i0 + 0) * 49 + w] * rs);
        o.y = (short)f2bf(Sm[buf][(i0 + 1) * 49 + w] * rs);
        o.z = (short)f2bf(Sm[buf][(i0 + 2) * 49 + w] * rs);
        o.w = (short)f2bf(Sm[buf][(i0 + 3) * 49 + w] * rs);
        *(short4*)&dst[id * 4] = o;
      }
    }
  } else {
    // ---------------- COL ----------------
    const int bid2 = bid - 512;
    const int hg = bid2 & 15, n = (bid2 >> 4) & 7, b = bid2 >> 7;
    const u32* base = qkv + (size_t)(b * 8 + n) * 48 * S_;
    {
      int h = hg * 3;
      for (int id = tid; id < 384; id += 256) {
        cqp[0][id] = base[(size_t)(16 + id / 48) * S_ + h * 48 + (id % 48)];
        ckp[0][id] = base[(size_t)(24 + id / 48) * S_ + h * 48 + (id % 48)];
      }
    }
    __syncthreads();
    for (int hh = 0; hh < 3; hh++) {
      const int buf = hh & 1;
      const int h = hg * 3 + hh;
      for (int id = tid; id < 2304; id += 256) {
        int w = id / 48, j = id % 48;
        float t = 0.f;
#pragma unroll
        for (int d8 = 0; d8 < 8; d8++) {
          u32 c = ckp[buf][d8 * 48 + w], a = cqp[buf][d8 * 48 + j];
          t += bflo(c) * bflo(a) + bfhi(c) * bfhi(a);
        }
        Sm[buf][w * 49 + j] = t * 0.25f;
      }
      if (hh < 2) {
        int hn = h + 1;
        for (int id = tid; id < 384; id += 256) {
          cqp[buf ^ 1][id] = base[(size_t)(16 + id / 48) * S_ + hn * 48 + (id % 48)];
          ckp[buf ^ 1][id] = base[(size_t)(24 + id / 48) * S_ + hn * 48 + (id % 48)];
        }
      }
      __syncthreads();
      if (tid < 192) {
        int w = tid >> 2, e = tid & 3;
        float m = -1e30f;
        for (int j = e; j < 48; j += 4) m = fmaxf(m, Sm[buf][w * 49 + j]);
        m = fmaxf(m, __shfl_xor(m, 1));
        m = fmaxf(m, __shfl_xor(m, 2));
        float s = 0.f;
        for (int j = e; j < 48; j += 4) {
          float ev = __expf(Sm[buf][w * 49 + j] - m);
          Sm[buf][w * 49 + j] = ev;
          s += ev;
        }
        s += __shfl_xor(s, 1);
        s += __shfl_xor(s, 2);
        red1[buf][w] = 1.0f / s;
      }
      __syncthreads();
      u16* dst = awF + ((size_t)(b * 8 + n) * 48 + h) * 3072;
      for (int id = tid; id < 384; id += 256) {
        int nt = id / 128, rem = id % 128, ks = rem / 64, l = rem % 64;
        int w = nt * 16 + (l & 15);
        int j0 = ks * 32 + ((l >> 4) << 3);
        float rs = red1[buf][w];
        u16 t8[8];
#pragma unroll
        for (int e = 0; e < 8; e++) {
          int j = j0 + e;
          t8[e] = (j < 48) ? f2bf(Sm[buf][w * 49 + j] * rs) : (u16)0;
        }
        short4 o0, o1;
        o0.x = (short)t8[0]; o0.y = (short)t8[1]; o0.z = (short)t8[2]; o0.w = (short)t8[3];
        o1.x = (short)t8[4]; o1.y = (short)t8[5]; o1.z = (short)t8[6]; o1.w = (short)t8[7];
        *(short4*)&dst[id * 8]     = o0;
        *(short4*)&dst[id * 8 + 4] = o1;
      }
    }
  }
}

// ---------------------------------------------------------------------------
// Main contraction + PE conv (r18 geometry, packed-v staging); epilogue now
// writes yP as PACKED h|l u32 (split_transpose's output, done in-place).
// ---------------------------------------------------------------------------
__global__ __launch_bounds__(256) void attn_main_kernel(
    const u32* __restrict__ qkv, const u16* __restrict__ arF,
    const u16* __restrict__ awF, const float* __restrict__ pe_w,
    const float* __restrict__ pe_b, u32* __restrict__ yP)
{
  __shared__ u16 vA[96 * 72];         // 13824 B
  const int id0 = blockIdx.x;
  const int n = id0 & 7;              // XCD swizzle
  const int rest = id0 >> 3;          // 0..255
  const int b = rest >> 6;
  const int inner = rest & 63;
  const int dchunk = inner >> 2;      // 0..15 (one v-pair each)
  const int hc = inner & 3;
  const int tid = threadIdx.x;
  const int wave = tid >> 6, lane = tid & 63;
  const int dl = wave >> 1, half = wave & 1;
  const int h0 = hc * 12 + half * 6;
  const int lr = lane & 15, lg = lane >> 4;

  for (int id = tid; id < 96 * 24; id += 256) {
    int row = id / 24, col = 48 + id % 24;
    vA[row * 72 + col] = 0;
  }
  const u32* vrow = qkv + ((size_t)(b * 8 + n) * 48 + 32 + dchunk) * S_;
  for (int id = tid; id < 576; id += 256) {
    int i = id / 12, j4 = (id % 12) * 4;
    uint4 v = *(const uint4*)&vrow[i * 48 + j4];
    short4 lo, hi;
    lo.x = (short)(v.x & 0xffff); hi.x = (short)(v.x >> 16);
    lo.y = (short)(v.y & 0xffff); hi.y = (short)(v.y >> 16);
    lo.z = (short)(v.z & 0xffff); hi.z = (short)(v.z >> 16);
    lo.w = (short)(v.w & 0xffff); hi.w = (short)(v.w >> 16);
    *(short4*)&vA[i * 72 + j4] = lo;
    *(short4*)&vA[(48 + i) * 72 + j4] = hi;
  }
  __syncthreads();   // the only barrier

  const size_t bn48 = (size_t)(b * 8 + n) * 48;
  const int c = n * 32 + dchunk * 2 + dl;
  float pw[9];
#pragma unroll
  for (int t = 0; t < 9; t++) pw[t] = pe_w[c * 9 + t];
  const float pb = pe_b[c];
  u32* yg = yP + ((size_t)b * 256 + c) * S_;
  const int vrow0 = dl * 48;

  for (int hh = 0; hh < 6; hh++) {
    int h = h0 + hh;
    const u16* awg = awF + (bn48 + h) * 3072;
    const u16* arg = arF + (bn48 + h) * 2304;

    bf16x8 bf0[3], bf1[3];
#pragma unroll
    for (int nt = 0; nt < 3; nt++) {
      bf0[nt] = *(const bf16x8*)&awg[nt * 1024 + lane * 8];
      bf1[nt] = *(const bf16x8*)&awg[nt * 1024 + 512 + lane * 8];
    }

    f32x4 acc[3][3];
#pragma unroll
    for (int mt = 0; mt < 3; mt++)
#pragma unroll
      for (int nt = 0; nt < 3; nt++) acc[mt][nt] = (f32x4){0.f, 0.f, 0.f, 0.f};

#pragma unroll
    for (int mt = 0; mt < 3; mt++) {
      bf16x8 a0 = *(const bf16x8*)&vA[(vrow0 + mt * 16 + lr) * 72 + lg * 8];
      bf16x8 a1 = *(const bf16x8*)&vA[(vrow0 + mt * 16 + lr) * 72 + 32 + lg * 8];
#pragma unroll
      for (int nt = 0; nt < 3; nt++) {
        acc[mt][nt] = __builtin_amdgcn_mfma_f32_16x16x32_bf16(a0, bf0[nt], acc[mt][nt], 0, 0, 0);
        acc[mt][nt] = __builtin_amdgcn_mfma_f32_16x16x32_bf16(a1, bf1[nt], acc[mt][nt], 0, 0, 0);
      }
    }

    float pv[3];
#pragma unroll
    for (int nt = 0; nt < 3; nt++) {
      float p = 0.f;
#pragma unroll
      for (int mt = 0; mt < 3; mt++) {
        short4 s = *(const short4*)&arg[(nt * 3 + mt) * 256 + lane * 4];
        p += bf2f((u16)s.x) * acc[mt][nt][0] + bf2f((u16)s.y) * acc[mt][nt][1]
           + bf2f((u16)s.z) * acc[mt][nt][2] + bf2f((u16)s.w) * acc[mt][nt][3];
      }
      p += __shfl_xor(p, 16);
      p += __shfl_xor(p, 32);
      pv[nt] = p;
    }

    if (lane < 48) {
      float a = (lane < 16) ? pv[0] : (lane < 32 ? pv[1] : pv[2]);
      a += pb;
      int ww = lane;
#pragma unroll
      for (int kh = -1; kh <= 1; kh++) {
        int ih = h + kh;
        if (ih < 0 || ih > 47) continue;
#pragma unroll
        for (int kw = -1; kw <= 1; kw++) {
          int jw = ww + kw;
          if (jw < 0 || jw > 47) continue;
          a += pw[(kh + 1) * 3 + (kw + 1)] * bf2f(vA[(vrow0 + ih) * 72 + jw]);
        }
      }
      u16 hh16 = f2bf(a);
      u16 ll16 = f2bf(a - bf2f(hh16));
      yg[h * 48 + ww] = (u32)hh16 | ((u32)ll16 << 16);
    }
  }
}

// ---------------------------------------------------------------------------
extern "C" void kernel_launch(void* const* d_in, const int* in_sizes, int n_in,
                              void* d_out, int out_size, void* d_ws, size_t ws_size,
                              hipStream_t stream) {
  const float* x      = (const float*)d_in[0];
  const float* rcv_w  = (const float*)d_in[1];
  const float* rcv_b  = (const float*)d_in[2];
  const float* pe_w   = (const float*)d_in[3];
  const float* pe_b   = (const float*)d_in[4];
  const float* proj_w = (const float*)d_in[5];
  const float* proj_b = (const float*)d_in[6];
  float* out = (float*)d_out;

  char* ws = (char*)d_ws;
  u32*   qkvP = (u32*)ws;                          // 0          14,155,776 B
  u16*   arF = (u16*)(ws + 14155776);              //  7,077,888 B
  u16*   awF = (u16*)(ws + 21233664);              //  9,437,184 B
  u16*   xTh = (u16*)(ws + 30670848);              //  4,718,592 B
  u32*   yP  = (u32*)(ws + 35389440);              //  9,437,184 B (packed h|l)
  u16*   Whr = (u16*)(ws + 44826624);              //    393,216 B
  u16*   Wlr = (u16*)(ws + 45219840);              //    393,216 B
  u16*   Whp = (u16*)(ws + 45613056);              //    131,072 B
  u16*   Wlp = (u16*)(ws + 45744128);              //    131,072 B (end ~45.9 MB)

  prep_kernel<<<dim3(832), 256, 0, stream>>>(rcv_w, Whr, Wlr, proj_w, Whp, Wlp, x, xTh);
  gemm_mfma_kernel<<<dim3(72 * 12), 256, 0, stream>>>(Whr, Wlr, rcv_b, xTh, qkvP);
  scores_kernel<<<dim3(1024), 256, 0, stream>>>(qkvP, arF, awF);
  attn_main_kernel<<<dim3(2048), 256, 0, stream>>>(qkvP, arF, awF, pe_w, pe_b, yP);
  gemm_n64_kernel<<<dim3(576), 256, 0, stream>>>(Whp, Wlp, proj_b, yP, out);
}